// Round 1
// baseline (192.824 us; speedup 1.0000x reference)
//
#include <hip/hip_runtime.h>
#include <math.h>

// GraspCVAE loss, MI355X. Structure:
//   init_kernel  : zero 8 accumulators, set per-hand-point min arrays to +inf
//   obj_kernel   : per obj point: NN to recon / gt / prior (LDS-staged targets),
//                  computes penetr, n_pts, contact, consistency, loss_o partials
//   hand_kernel  : per hand point x obj-chunk: min d2 via atomicMin(bitcast)
//   tail_kernel  : loss_h from mins + recon_loss + KLD partials
//   final_kernel : combine scalar
//
// All data (~1.5MB) is L2-resident; kernels are VALU-bound.

#define NB 32
#define NH 778
#define NO 3000
#define NZ 64
#define NP 204
#define OBJ_TILES 12   // ceil(3000/256)
#define OC_NUM 6       // obj chunks in hand kernel
#define OC_SIZE 500

__device__ __constant__ int c_prior[NP] = {
  // F1 (36)
  697,698,699,700,712,713,714,715,737,738,739,740,741,743,744,745,746,748,749,750,
  753,754,755,756,757,758,759,760,761,762,763,764,765,766,767,768,
  // F2 (46)
  46,47,48,49,164,165,166,167,194,195,223,237,238,280,281,298,301,317,320,323,
  324,325,326,327,328,329,330,331,332,333,340,341,342,343,344,345,346,347,348,349,
  350,351,352,353,354,355,
  // F3 (40)
  356,357,358,359,375,376,386,387,396,397,402,403,413,429,433,434,435,436,437,438,
  439,440,441,442,443,444,452,453,454,455,456,459,460,461,462,463,464,465,466,467,
  // F4 (37)
  468,469,470,471,484,485,486,496,497,506,507,513,514,524,545,546,547,548,549,550,
  551,552,553,555,563,564,565,566,567,570,572,573,574,575,576,577,578,
  // F5 (37)
  580,581,582,583,600,601,602,614,615,624,625,630,631,641,663,664,665,666,667,668,
  670,672,680,681,682,683,684,686,687,688,689,690,691,692,693,694,695,
  // F0 (8)
  73,96,98,99,772,774,775,777
};

__device__ inline float wave_sum(float v) {
  v += __shfl_down(v, 32);
  v += __shfl_down(v, 16);
  v += __shfl_down(v, 8);
  v += __shfl_down(v, 4);
  v += __shfl_down(v, 2);
  v += __shfl_down(v, 1);
  return v;
}

__global__ void init_kernel(float* accs, unsigned int* mins, int nmins) {
  int t = blockIdx.x * blockDim.x + threadIdx.x;
  if (t < 8) accs[t] = 0.0f;
  if (t < nmins) mins[t] = 0x7F800000u;  // +inf
}

// accs: 0 penetr, 1 npts, 2 contact, 3 consist, 4 loss_o, 5 loss_h, 6 recon_sq, 7 kld
__global__ __launch_bounds__(256) void obj_kernel(
    const float* __restrict__ recon, const float* __restrict__ gt,
    const float* __restrict__ rnorm, const float* __restrict__ gnorm,
    const float* __restrict__ obj, float* __restrict__ accs)
{
  __shared__ float sR[NH * 3];
  __shared__ float sG[NH * 3];
  __shared__ float sRN[NH * 3];
  __shared__ float sGN[NH * 3];
  __shared__ float red[4][5];

  const int b = blockIdx.x / OBJ_TILES;
  const int tile = blockIdx.x % OBJ_TILES;
  const int tid = threadIdx.x;

  const float* Rb  = recon + (size_t)b * NH * 3;
  const float* Gb  = gt    + (size_t)b * NH * 3;
  const float* RNb = rnorm + (size_t)b * NH * 3;
  const float* GNb = gnorm + (size_t)b * NH * 3;
  for (int i = tid; i < NH * 3; i += 256) {
    sR[i]  = Rb[i];
    sG[i]  = Gb[i];
    sRN[i] = RNb[i];
    sGN[i] = GNb[i];
  }
  __syncthreads();

  const int o = tile * 256 + tid;
  float penetr = 0.f, nptsv = 0.f, contactv = 0.f, consistv = 0.f, lossov = 0.f;

  if (o < NO) {
    const float* op = obj + ((size_t)b * NO + o) * 3;
    const float ox = op[0], oy = op[1], oz = op[2];

    float minR = 1e30f, minG = 1e30f;
    int idxR = 0, idxG = 0;
    for (int j = 0; j < NH; ++j) {
      float dx = ox - sR[3*j], dy = oy - sR[3*j+1], dz = oz - sR[3*j+2];
      float d2 = dx*dx + dy*dy + dz*dz;
      if (d2 < minR) { minR = d2; idxR = j; }
      float ex = ox - sG[3*j], ey = oy - sG[3*j+1], ez = oz - sG[3*j+2];
      float e2 = ex*ex + ey*ey + ez*ez;
      if (e2 < minG) { minG = e2; idxG = j; }
    }
    float minP = 1e30f;
    for (int k = 0; k < NP; ++k) {
      int j = c_prior[k];
      float dx = ox - sR[3*j], dy = oy - sR[3*j+1], dz = oz - sR[3*j+2];
      float d2 = dx*dx + dy*dy + dz*dz;
      minP = fminf(minP, d2);
    }

    // recon side: signed dist + interior
    float dotR = (ox - sR[3*idxR]) * sRN[3*idxR]
               + (oy - sR[3*idxR+1]) * sRN[3*idxR+1]
               + (oz - sR[3*idxR+2]) * sRN[3*idxR+2];
    float sgnR = (dotR > 0.f) ? 1.f : ((dotR < 0.f) ? -1.f : 0.f);
    float o2h = sqrtf(minR) * sgnR;
    // gt side
    float dotG = (ox - sG[3*idxG]) * sGN[3*idxG]
               + (oy - sG[3*idxG+1]) * sGN[3*idxG+1]
               + (oz - sG[3*idxG+2]) * sGN[3*idxG+2];
    float sgnG = (dotG > 0.f) ? 1.f : ((dotG < 0.f) ? -1.f : 0.f);
    float o2hg = sqrtf(minG) * sgnG;

    bool interior = dotR < 0.f;            // dot(nn - obj, n) > 0
    bool cmap  = sqrtf(minG) < 0.005f;
    bool rcmap = sqrtf(minR) < 0.005f;

    penetr   = interior ? minR : 0.f;
    nptsv    = cmap ? 1.f : 0.f;
    contactv = cmap ? minP : 0.f;
    consistv = (cmap && rcmap) ? 1.f : 0.f;
    float w = (o2h < 0.f) ? 1.5f
            : (((o2hg < 0.01f) && (o2hg > -0.005f)) ? 1.f : 0.1f);
    lossov = fabsf(o2h - o2hg) * w;
  }

  float vals[5] = {penetr, nptsv, contactv, consistv, lossov};
  const int lane = tid & 63, wv = tid >> 6;
  for (int q = 0; q < 5; ++q) {
    float s = wave_sum(vals[q]);
    if (lane == 0) red[wv][q] = s;
  }
  __syncthreads();
  if (tid < 5) {
    float s = red[0][tid] + red[1][tid] + red[2][tid] + red[3][tid];
    atomicAdd(&accs[tid], s);
  }
}

// hand -> obj min distances, obj chunked 6x for occupancy, atomicMin combine
__global__ __launch_bounds__(256) void hand_kernel(
    const float* __restrict__ recon, const float* __restrict__ gt,
    const float* __restrict__ obj,
    unsigned int* __restrict__ minRarr, unsigned int* __restrict__ minGarr)
{
  __shared__ float sO[OC_SIZE * 3];
  const int oc = blockIdx.x % OC_NUM;
  const int pt = (blockIdx.x / OC_NUM) % 4;
  const int b  = blockIdx.x / (OC_NUM * 4);

  const float* Ob = obj + ((size_t)b * NO + oc * OC_SIZE) * 3;
  for (int i = threadIdx.x; i < OC_SIZE * 3; i += 256) sO[i] = Ob[i];
  __syncthreads();

  const int j = pt * 256 + threadIdx.x;
  if (j < NH) {
    const float* rp = recon + ((size_t)b * NH + j) * 3;
    const float* gp = gt    + ((size_t)b * NH + j) * 3;
    const float rx = rp[0], ry = rp[1], rz = rp[2];
    const float gx = gp[0], gy = gp[1], gz = gp[2];
    float mR = 1e30f, mG = 1e30f;
    for (int k = 0; k < OC_SIZE; ++k) {
      float x = sO[3*k], y = sO[3*k+1], z = sO[3*k+2];
      float dx = rx - x, dy = ry - y, dz = rz - z;
      float dr = dx*dx + dy*dy + dz*dz;
      float ex = gx - x, ey = gy - y, ez = gz - z;
      float dg = ex*ex + ey*ey + ez*ez;
      mR = fminf(mR, dr);
      mG = fminf(mG, dg);
    }
    const int base = b * NH + j;
    atomicMin(&minRarr[base], __float_as_uint(mR));  // positive floats: uint order == float order
    atomicMin(&minGarr[base], __float_as_uint(mG));
  }
}

// Fallback if ws too small for min arrays: full 3000-loop per hand point
__global__ __launch_bounds__(256) void hand_full_kernel(
    const float* __restrict__ recon, const float* __restrict__ gt,
    const float* __restrict__ obj, const float* __restrict__ vw,
    float* __restrict__ accs)
{
  __shared__ float sO[OC_SIZE * 3];
  __shared__ float red[4];
  const int b = blockIdx.x >> 2;
  const int j = ((blockIdx.x & 3) << 8) + threadIdx.x;
  const bool valid = j < NH;
  float rx = 0.f, ry = 0.f, rz = 0.f, gx = 0.f, gy = 0.f, gz = 0.f;
  if (valid) {
    const float* rp = recon + ((size_t)b * NH + j) * 3;
    const float* gp = gt    + ((size_t)b * NH + j) * 3;
    rx = rp[0]; ry = rp[1]; rz = rp[2];
    gx = gp[0]; gy = gp[1]; gz = gp[2];
  }
  float mR = 1e30f, mG = 1e30f;
  for (int oc = 0; oc < OC_NUM; ++oc) {
    __syncthreads();
    const float* Ob = obj + ((size_t)b * NO + oc * OC_SIZE) * 3;
    for (int i = threadIdx.x; i < OC_SIZE * 3; i += 256) sO[i] = Ob[i];
    __syncthreads();
    if (valid) {
      for (int k = 0; k < OC_SIZE; ++k) {
        float x = sO[3*k], y = sO[3*k+1], z = sO[3*k+2];
        float dx = rx - x, dy = ry - y, dz = rz - z;
        float ex = gx - x, ey = gy - y, ez = gz - z;
        mR = fminf(mR, dx*dx + dy*dy + dz*dz);
        mG = fminf(mG, ex*ex + ey*ey + ez*ez);
      }
    }
  }
  float lossh = valid ? fabsf(sqrtf(mR) - sqrtf(mG)) * powf(vw[j], 0.4f) : 0.f;
  const int lane = threadIdx.x & 63, wv = threadIdx.x >> 6;
  float s = wave_sum(lossh);
  if (lane == 0) red[wv] = s;
  __syncthreads();
  if (threadIdx.x == 0)
    atomicAdd(&accs[5], red[0] + red[1] + red[2] + red[3]);
}

__global__ __launch_bounds__(256) void tail_kernel(
    const float* __restrict__ recon, const float* __restrict__ gt,
    const float* __restrict__ mean, const float* __restrict__ logv,
    const float* __restrict__ vw,
    const unsigned int* __restrict__ mRarr, const unsigned int* __restrict__ mGarr,
    float* __restrict__ accs, int use_mins)
{
  __shared__ float red[4][3];
  const int t = blockIdx.x * 256 + threadIdx.x;
  float lossh = 0.f, rsum = 0.f, ksum = 0.f;
  if (t < NB * NH) {
    const float* rp = recon + (size_t)t * 3;
    const float* gp = gt + (size_t)t * 3;
    float d0 = rp[0] - gp[0], d1 = rp[1] - gp[1], d2 = rp[2] - gp[2];
    rsum = d0*d0 + d1*d1 + d2*d2;
    if (use_mins) {
      int j = t % NH;
      float h2o  = sqrtf(__uint_as_float(mRarr[t]));
      float h2og = sqrtf(__uint_as_float(mGarr[t]));
      lossh = fabsf(h2o - h2og) * powf(vw[j], 0.4f);
    }
  }
  if (t < NB * NZ) {
    float m = mean[t], lv = logv[t];
    ksum = 1.f + lv - m * m - expf(lv);
  }
  float vals[3] = {lossh, rsum, ksum};
  const int lane = threadIdx.x & 63, wv = threadIdx.x >> 6;
  for (int q = 0; q < 3; ++q) {
    float s = wave_sum(vals[q]);
    if (lane == 0) red[wv][q] = s;
  }
  __syncthreads();
  if (threadIdx.x < 3) {
    float s = red[0][threadIdx.x] + red[1][threadIdx.x] + red[2][threadIdx.x] + red[3][threadIdx.x];
    atomicAdd(&accs[5 + threadIdx.x], s);
  }
}

__global__ void final_kernel(const float* __restrict__ a, float* __restrict__ out) {
  const float recon_loss = a[6] / (float)NB;
  const float kld = -0.5f * a[7] / (float)NB * 10.f;
  const float penetr = 100.f * a[0] / (float)NB;
  const float npts = a[1];
  const float contact = (npts > 0.f) ? (3000.f * a[2] / ((float)NB * npts)) : 0.f;
  const float consistency = -5.f * a[3] / (npts + 0.0001f);
  const float lossh = 35.f * (1.f - 0.005f) * (a[5] / (float)(NB * NH));
  const float losso = 30.f * (1.f - 0.005f) * (a[4] / (float)(NB * NO));
  out[0] = recon_loss + 0.1f * kld + 1000.f * penetr + 10.f * contact
         + 10.f * consistency + lossh + losso;
}

extern "C" void kernel_launch(void* const* d_in, const int* in_sizes, int n_in,
                              void* d_out, int out_size, void* d_ws, size_t ws_size,
                              hipStream_t stream) {
  const float* recon = (const float*)d_in[0];
  const float* gt    = (const float*)d_in[1];
  const float* rnorm = (const float*)d_in[2];
  const float* gnorm = (const float*)d_in[3];
  const float* obj   = (const float*)d_in[4];
  const float* mean  = (const float*)d_in[5];
  const float* logv  = (const float*)d_in[6];
  const float* vw    = (const float*)d_in[7];
  float* out = (float*)d_out;

  float* accs = (float*)d_ws;
  unsigned int* mins = (unsigned int*)(accs + 8);
  const size_t needed = (8 + 2 * NB * NH) * sizeof(float);
  const bool use_mins = ws_size >= needed;
  const int nmins = use_mins ? 2 * NB * NH : 0;

  {
    int total = 8 + 2 * NB * NH;
    int blocks = (total + 255) / 256;
    init_kernel<<<blocks, 256, 0, stream>>>(accs, mins, nmins);
  }

  obj_kernel<<<NB * OBJ_TILES, 256, 0, stream>>>(recon, gt, rnorm, gnorm, obj, accs);

  if (use_mins) {
    hand_kernel<<<NB * 4 * OC_NUM, 256, 0, stream>>>(recon, gt, obj, mins, mins + NB * NH);
  } else {
    hand_full_kernel<<<NB * 4, 256, 0, stream>>>(recon, gt, obj, vw, accs);
  }

  {
    int blocks = (NB * NH + 255) / 256;
    tail_kernel<<<blocks, 256, 0, stream>>>(recon, gt, mean, logv, vw,
                                            mins, mins + NB * NH, accs,
                                            use_mins ? 1 : 0);
  }

  final_kernel<<<1, 1, 0, stream>>>(accs, out);
}

// Round 2
// 132.168 us; speedup vs baseline: 1.4589x; 1.4589x over previous
//
#include <hip/hip_runtime.h>
#include <math.h>

// GraspCVAE loss, MI355X — round 2.
// Structure (main path, needs ~1.74 MB ws):
//   init_kernel : zero accs, +inf hand-min arrays, ~0ull obj packed argmin
//   mega1       : blocks [0,768)  : obj->hand NN, j-loop split in half,
//                                   packed (d2<<32|idx) atomicMin(u64)
//                 blocks [768,1536): hand->obj NN, obj chunked 6x, atomicMin(u32)
//   mega2       : blocks [0,384)  : obj finalize (prior NN, penetr/contact/
//                                   consistency/loss_o partials)
//                 blocks [384,482): loss_h + recon_loss + KLD partials
//   final_kernel: combine scalar
// Inner loops use d2 = |h|^2 - 2 o.h + |o|^2 with LDS float4 (x,y,z,|p|^2):
// 1x ds_read_b128 + 3 FMA per candidate per target.
// Fallback path (tiny ws): round-1 monolithic kernels.

#define NB 32
#define NH 778
#define NO 3000
#define NZ 64
#define NP 204
#define JHALF 389         // NH/2
#define OBJ_TILES 12      // ceil(3000/256)
#define OC_NUM 6
#define OC_SIZE 500

typedef unsigned int uint32;
typedef unsigned long long ull;

__device__ __constant__ int c_prior[NP] = {
  697,698,699,700,712,713,714,715,737,738,739,740,741,743,744,745,746,748,749,750,
  753,754,755,756,757,758,759,760,761,762,763,764,765,766,767,768,
  46,47,48,49,164,165,166,167,194,195,223,237,238,280,281,298,301,317,320,323,
  324,325,326,327,328,329,330,331,332,333,340,341,342,343,344,345,346,347,348,349,
  350,351,352,353,354,355,
  356,357,358,359,375,376,386,387,396,397,402,403,413,429,433,434,435,436,437,438,
  439,440,441,442,443,444,452,453,454,455,456,459,460,461,462,463,464,465,466,467,
  468,469,470,471,484,485,486,496,497,506,507,513,514,524,545,546,547,548,549,550,
  551,552,553,555,563,564,565,566,567,570,572,573,574,575,576,577,578,
  580,581,582,583,600,601,602,614,615,624,625,630,631,641,663,664,665,666,667,668,
  670,672,680,681,682,683,684,686,687,688,689,690,691,692,693,694,695,
  73,96,98,99,772,774,775,777
};

__device__ inline float wave_sum(float v) {
  v += __shfl_down(v, 32);
  v += __shfl_down(v, 16);
  v += __shfl_down(v, 8);
  v += __shfl_down(v, 4);
  v += __shfl_down(v, 2);
  v += __shfl_down(v, 1);
  return v;
}

// ws layout (main path)
#define N_MINH (2 * NB * NH)       // 49792 u32
#define N_PACK (2 * NB * NO)       // 192000 u64

__global__ void init_kernel(float* accs, uint32* minH, ull* packO) {
  int t = blockIdx.x * blockDim.x + threadIdx.x;
  if (t < 8) accs[t] = 0.0f;
  if (t < N_MINH) minH[t] = 0x7F800000u;   // +inf
  if (t < N_PACK) packO[t] = ~0ull;
}

// accs: 0 penetr, 1 npts, 2 contact, 3 consist, 4 loss_o, 5 loss_h, 6 recon_sq, 7 kld
__global__ __launch_bounds__(256) void mega1(
    const float* __restrict__ recon, const float* __restrict__ gt,
    const float* __restrict__ obj,
    uint32* __restrict__ minHR, uint32* __restrict__ minHG,
    ull* __restrict__ packR, ull* __restrict__ packG)
{
  const int bid = blockIdx.x;
  const int tid = threadIdx.x;

  if (bid < NB * OBJ_TILES * 2) {
    // ---- obj-side NN, j-split ----
    __shared__ float4 sR[JHALF];
    __shared__ float4 sG[JHALF];
    const int half = bid & 1;
    const int tile = (bid >> 1) % OBJ_TILES;
    const int b = bid / (OBJ_TILES * 2);
    const int jbase = half * JHALF;

    for (int i = tid; i < JHALF; i += 256) {
      const float* p = recon + ((size_t)b * NH + jbase + i) * 3;
      float x = p[0], y = p[1], z = p[2];
      sR[i] = make_float4(x, y, z, x*x + y*y + z*z);
      const float* q = gt + ((size_t)b * NH + jbase + i) * 3;
      float gx = q[0], gy = q[1], gz = q[2];
      sG[i] = make_float4(gx, gy, gz, gx*gx + gy*gy + gz*gz);
    }
    __syncthreads();

    const int o = tile * 256 + tid;
    if (o >= NO) return;
    const float* op = obj + ((size_t)b * NO + o) * 3;
    const float ox = op[0], oy = op[1], oz = op[2];
    const float nx = -2.f * ox, ny = -2.f * oy, nz = -2.f * oz;
    const float o2 = ox*ox + oy*oy + oz*oz;

    float bR = 3.4e38f, bG = 3.4e38f;
    int iR = jbase, iG = jbase;
    for (int i = 0; i < JHALF; ++i) {
      float4 h = sR[i];
      float t = fmaf(nx, h.x, h.w);
      t = fmaf(ny, h.y, t);
      t = fmaf(nz, h.z, t);
      if (t < bR) { bR = t; iR = jbase + i; }
      float4 g = sG[i];
      float u = fmaf(nx, g.x, g.w);
      u = fmaf(ny, g.y, u);
      u = fmaf(nz, g.z, u);
      if (u < bG) { bG = u; iG = jbase + i; }
    }
    float d2R = fmaxf(bR + o2, 0.f);
    float d2G = fmaxf(bG + o2, 0.f);
    const size_t base = (size_t)b * NO + o;
    atomicMin(&packR[base], ((ull)__float_as_uint(d2R) << 32) | (uint32)iR);
    atomicMin(&packG[base], ((ull)__float_as_uint(d2G) << 32) | (uint32)iG);
  } else {
    // ---- hand-side NN, obj chunked ----
    __shared__ float4 sO[OC_SIZE];
    const int bid2 = bid - NB * OBJ_TILES * 2;
    const int oc = bid2 % OC_NUM;
    const int pt = (bid2 / OC_NUM) % 4;
    const int b = bid2 / (OC_NUM * 4);

    const float* Ob = obj + ((size_t)b * NO + oc * OC_SIZE) * 3;
    for (int i = tid; i < OC_SIZE; i += 256) {
      float x = Ob[3*i], y = Ob[3*i+1], z = Ob[3*i+2];
      sO[i] = make_float4(x, y, z, x*x + y*y + z*z);
    }
    __syncthreads();

    const int j = pt * 256 + tid;
    if (j >= NH) return;
    const float* rp = recon + ((size_t)b * NH + j) * 3;
    const float* gp = gt    + ((size_t)b * NH + j) * 3;
    const float rx = rp[0], ry = rp[1], rz = rp[2];
    const float gx = gp[0], gy = gp[1], gz = gp[2];
    const float nrx = -2.f * rx, nry = -2.f * ry, nrz = -2.f * rz;
    const float ngx = -2.f * gx, ngy = -2.f * gy, ngz = -2.f * gz;
    const float r2 = rx*rx + ry*ry + rz*rz;
    const float g2 = gx*gx + gy*gy + gz*gz;

    float mR = 3.4e38f, mG = 3.4e38f;
    for (int k = 0; k < OC_SIZE; ++k) {
      float4 o4 = sO[k];
      float t = fmaf(nrx, o4.x, o4.w);
      t = fmaf(nry, o4.y, t);
      t = fmaf(nrz, o4.z, t);
      mR = fminf(mR, t);
      float u = fmaf(ngx, o4.x, o4.w);
      u = fmaf(ngy, o4.y, u);
      u = fmaf(ngz, o4.z, u);
      mG = fminf(mG, u);
    }
    float d2R = fmaxf(mR + r2, 0.f);
    float d2G = fmaxf(mG + g2, 0.f);
    const int base = b * NH + j;
    atomicMin(&minHR[base], __float_as_uint(d2R));
    atomicMin(&minHG[base], __float_as_uint(d2G));
  }
}

__global__ __launch_bounds__(256) void mega2(
    const float* __restrict__ recon, const float* __restrict__ gt,
    const float* __restrict__ rnorm, const float* __restrict__ gnorm,
    const float* __restrict__ obj,
    const float* __restrict__ mean, const float* __restrict__ logv,
    const float* __restrict__ vw,
    const uint32* __restrict__ minHR, const uint32* __restrict__ minHG,
    const ull* __restrict__ packR, const ull* __restrict__ packG,
    float* __restrict__ accs)
{
  __shared__ float4 sP[NP];
  __shared__ float red[4][5];
  const int bid = blockIdx.x;
  const int tid = threadIdx.x;
  const int lane = tid & 63, wv = tid >> 6;

  if (bid < NB * OBJ_TILES) {
    // ---- obj finalize ----
    const int b = bid / OBJ_TILES;
    const int tile = bid % OBJ_TILES;
    if (tid < NP) {
      int j = c_prior[tid];
      const float* p = recon + ((size_t)b * NH + j) * 3;
      float x = p[0], y = p[1], z = p[2];
      sP[tid] = make_float4(x, y, z, x*x + y*y + z*z);
    }
    __syncthreads();

    const int o = tile * 256 + tid;
    float penetr = 0.f, nptsv = 0.f, contactv = 0.f, consistv = 0.f, lossov = 0.f;
    if (o < NO) {
      const float* op = obj + ((size_t)b * NO + o) * 3;
      const float ox = op[0], oy = op[1], oz = op[2];
      const float nx = -2.f * ox, ny = -2.f * oy, nz = -2.f * oz;
      const float o2 = ox*ox + oy*oy + oz*oz;

      const size_t base = (size_t)b * NO + o;
      ull pR = packR[base], pG = packG[base];
      float d2R = __uint_as_float((uint32)(pR >> 32));
      float d2G = __uint_as_float((uint32)(pG >> 32));
      int idxR = (int)(uint32)pR, idxG = (int)(uint32)pG;

      float bP = 3.4e38f;
      for (int k = 0; k < NP; ++k) {
        float4 h = sP[k];
        float t = fmaf(nx, h.x, h.w);
        t = fmaf(ny, h.y, t);
        t = fmaf(nz, h.z, t);
        bP = fminf(bP, t);
      }
      float d2P = fmaxf(bP + o2, 0.f);

      const float* hR = recon + ((size_t)b * NH + idxR) * 3;
      const float* nR = rnorm + ((size_t)b * NH + idxR) * 3;
      float dotR = (ox - hR[0]) * nR[0] + (oy - hR[1]) * nR[1] + (oz - hR[2]) * nR[2];
      const float* hG = gt + ((size_t)b * NH + idxG) * 3;
      const float* nG = gnorm + ((size_t)b * NH + idxG) * 3;
      float dotG = (ox - hG[0]) * nG[0] + (oy - hG[1]) * nG[1] + (oz - hG[2]) * nG[2];

      float sgnR = (dotR > 0.f) ? 1.f : ((dotR < 0.f) ? -1.f : 0.f);
      float sgnG = (dotG > 0.f) ? 1.f : ((dotG < 0.f) ? -1.f : 0.f);
      float sR_ = sqrtf(d2R), sG_ = sqrtf(d2G);
      float o2h = sR_ * sgnR;
      float o2hg = sG_ * sgnG;

      bool interior = dotR < 0.f;
      bool cmap = sG_ < 0.005f;
      bool rcmap = sR_ < 0.005f;

      penetr   = interior ? d2R : 0.f;
      nptsv    = cmap ? 1.f : 0.f;
      contactv = cmap ? d2P : 0.f;
      consistv = (cmap && rcmap) ? 1.f : 0.f;
      float w = (o2h < 0.f) ? 1.5f
              : (((o2hg < 0.01f) && (o2hg > -0.005f)) ? 1.f : 0.1f);
      lossov = fabsf(o2h - o2hg) * w;
    }
    float vals[5] = {penetr, nptsv, contactv, consistv, lossov};
    for (int q = 0; q < 5; ++q) {
      float s = wave_sum(vals[q]);
      if (lane == 0) red[wv][q] = s;
    }
    __syncthreads();
    if (tid < 5) {
      float s = red[0][tid] + red[1][tid] + red[2][tid] + red[3][tid];
      atomicAdd(&accs[tid], s);
    }
  } else {
    // ---- tail: loss_h, recon_loss, KLD ----
    const int t = (bid - NB * OBJ_TILES) * 256 + tid;
    float lossh = 0.f, rsum = 0.f, ksum = 0.f;
    if (t < NB * NH) {
      const float* rp = recon + (size_t)t * 3;
      const float* gp = gt + (size_t)t * 3;
      float d0 = rp[0] - gp[0], d1 = rp[1] - gp[1], d2 = rp[2] - gp[2];
      rsum = d0*d0 + d1*d1 + d2*d2;
      int j = t % NH;
      float h2o  = sqrtf(__uint_as_float(minHR[t]));
      float h2og = sqrtf(__uint_as_float(minHG[t]));
      lossh = fabsf(h2o - h2og) * powf(vw[j], 0.4f);
    }
    if (t < NB * NZ) {
      float m = mean[t], lv = logv[t];
      ksum = 1.f + lv - m * m - expf(lv);
    }
    float vals[3] = {lossh, rsum, ksum};
    for (int q = 0; q < 3; ++q) {
      float s = wave_sum(vals[q]);
      if (lane == 0) red[wv][q] = s;
    }
    __syncthreads();
    if (tid < 3) {
      float s = red[0][tid] + red[1][tid] + red[2][tid] + red[3][tid];
      atomicAdd(&accs[5 + tid], s);
    }
  }
}

__global__ void final_kernel(const float* __restrict__ a, float* __restrict__ out) {
  const float recon_loss = a[6] / (float)NB;
  const float kld = -0.5f * a[7] / (float)NB * 10.f;
  const float penetr = 100.f * a[0] / (float)NB;
  const float npts = a[1];
  const float contact = (npts > 0.f) ? (3000.f * a[2] / ((float)NB * npts)) : 0.f;
  const float consistency = -5.f * a[3] / (npts + 0.0001f);
  const float lossh = 35.f * (1.f - 0.005f) * (a[5] / (float)(NB * NH));
  const float losso = 30.f * (1.f - 0.005f) * (a[4] / (float)(NB * NO));
  out[0] = recon_loss + 0.1f * kld + 1000.f * penetr + 10.f * contact
         + 10.f * consistency + lossh + losso;
}

// ================= fallback path (tiny ws): round-1 style =================
__global__ __launch_bounds__(256) void obj_mono(
    const float* __restrict__ recon, const float* __restrict__ gt,
    const float* __restrict__ rnorm, const float* __restrict__ gnorm,
    const float* __restrict__ obj, float* __restrict__ accs)
{
  __shared__ float4 sR[NH];
  __shared__ float4 sG[NH];
  __shared__ float red[4][5];
  const int b = blockIdx.x / OBJ_TILES;
  const int tile = blockIdx.x % OBJ_TILES;
  const int tid = threadIdx.x;

  for (int i = tid; i < NH; i += 256) {
    const float* p = recon + ((size_t)b * NH + i) * 3;
    float x = p[0], y = p[1], z = p[2];
    sR[i] = make_float4(x, y, z, x*x + y*y + z*z);
    const float* q = gt + ((size_t)b * NH + i) * 3;
    float gx = q[0], gy = q[1], gz = q[2];
    sG[i] = make_float4(gx, gy, gz, gx*gx + gy*gy + gz*gz);
  }
  __syncthreads();

  const int o = tile * 256 + tid;
  float penetr = 0.f, nptsv = 0.f, contactv = 0.f, consistv = 0.f, lossov = 0.f;
  if (o < NO) {
    const float* op = obj + ((size_t)b * NO + o) * 3;
    const float ox = op[0], oy = op[1], oz = op[2];
    const float nx = -2.f * ox, ny = -2.f * oy, nz = -2.f * oz;
    const float o2 = ox*ox + oy*oy + oz*oz;
    float bR = 3.4e38f, bG = 3.4e38f;
    int iR = 0, iG = 0;
    for (int i = 0; i < NH; ++i) {
      float4 h = sR[i];
      float t = fmaf(nx, h.x, h.w); t = fmaf(ny, h.y, t); t = fmaf(nz, h.z, t);
      if (t < bR) { bR = t; iR = i; }
      float4 g = sG[i];
      float u = fmaf(nx, g.x, g.w); u = fmaf(ny, g.y, u); u = fmaf(nz, g.z, u);
      if (u < bG) { bG = u; iG = i; }
    }
    float bP = 3.4e38f;
    for (int k = 0; k < NP; ++k) {
      float4 h = sR[c_prior[k]];
      float t = fmaf(nx, h.x, h.w); t = fmaf(ny, h.y, t); t = fmaf(nz, h.z, t);
      bP = fminf(bP, t);
    }
    float d2R = fmaxf(bR + o2, 0.f);
    float d2G = fmaxf(bG + o2, 0.f);
    float d2P = fmaxf(bP + o2, 0.f);
    float4 hR = sR[iR];
    const float* nR = rnorm + ((size_t)b * NH + iR) * 3;
    float dotR = (ox - hR.x) * nR[0] + (oy - hR.y) * nR[1] + (oz - hR.z) * nR[2];
    float4 hG = sG[iG];
    const float* nG = gnorm + ((size_t)b * NH + iG) * 3;
    float dotG = (ox - hG.x) * nG[0] + (oy - hG.y) * nG[1] + (oz - hG.z) * nG[2];
    float sgnR = (dotR > 0.f) ? 1.f : ((dotR < 0.f) ? -1.f : 0.f);
    float sgnG = (dotG > 0.f) ? 1.f : ((dotG < 0.f) ? -1.f : 0.f);
    float sR_ = sqrtf(d2R), sG_ = sqrtf(d2G);
    float o2h = sR_ * sgnR, o2hg = sG_ * sgnG;
    bool interior = dotR < 0.f;
    bool cmap = sG_ < 0.005f, rcmap = sR_ < 0.005f;
    penetr = interior ? d2R : 0.f;
    nptsv = cmap ? 1.f : 0.f;
    contactv = cmap ? d2P : 0.f;
    consistv = (cmap && rcmap) ? 1.f : 0.f;
    float w = (o2h < 0.f) ? 1.5f : (((o2hg < 0.01f) && (o2hg > -0.005f)) ? 1.f : 0.1f);
    lossov = fabsf(o2h - o2hg) * w;
  }
  float vals[5] = {penetr, nptsv, contactv, consistv, lossov};
  const int lane = tid & 63, wv = tid >> 6;
  for (int q = 0; q < 5; ++q) {
    float s = wave_sum(vals[q]);
    if (lane == 0) red[wv][q] = s;
  }
  __syncthreads();
  if (tid < 5) {
    float s = red[0][tid] + red[1][tid] + red[2][tid] + red[3][tid];
    atomicAdd(&accs[tid], s);
  }
}

__global__ __launch_bounds__(256) void hand_full(
    const float* __restrict__ recon, const float* __restrict__ gt,
    const float* __restrict__ obj, const float* __restrict__ vw,
    float* __restrict__ accs)
{
  __shared__ float4 sO[OC_SIZE];
  __shared__ float red[4];
  const int b = blockIdx.x >> 2;
  const int j = ((blockIdx.x & 3) << 8) + threadIdx.x;
  const bool valid = j < NH;
  float rx = 0, ry = 0, rz = 0, gx = 0, gy = 0, gz = 0;
  if (valid) {
    const float* rp = recon + ((size_t)b * NH + j) * 3;
    const float* gp = gt + ((size_t)b * NH + j) * 3;
    rx = rp[0]; ry = rp[1]; rz = rp[2];
    gx = gp[0]; gy = gp[1]; gz = gp[2];
  }
  const float nrx = -2.f*rx, nry = -2.f*ry, nrz = -2.f*rz;
  const float ngx = -2.f*gx, ngy = -2.f*gy, ngz = -2.f*gz;
  const float r2 = rx*rx + ry*ry + rz*rz, g2 = gx*gx + gy*gy + gz*gz;
  float mR = 3.4e38f, mG = 3.4e38f;
  for (int oc = 0; oc < OC_NUM; ++oc) {
    __syncthreads();
    const float* Ob = obj + ((size_t)b * NO + oc * OC_SIZE) * 3;
    for (int i = threadIdx.x; i < OC_SIZE; i += 256) {
      float x = Ob[3*i], y = Ob[3*i+1], z = Ob[3*i+2];
      sO[i] = make_float4(x, y, z, x*x + y*y + z*z);
    }
    __syncthreads();
    if (valid) {
      for (int k = 0; k < OC_SIZE; ++k) {
        float4 o4 = sO[k];
        float t = fmaf(nrx, o4.x, o4.w); t = fmaf(nry, o4.y, t); t = fmaf(nrz, o4.z, t);
        mR = fminf(mR, t);
        float u = fmaf(ngx, o4.x, o4.w); u = fmaf(ngy, o4.y, u); u = fmaf(ngz, o4.z, u);
        mG = fminf(mG, u);
      }
    }
  }
  float lossh = valid ? fabsf(sqrtf(fmaxf(mR + r2, 0.f)) - sqrtf(fmaxf(mG + g2, 0.f)))
                        * powf(vw[j], 0.4f) : 0.f;
  const int lane = threadIdx.x & 63, wv = threadIdx.x >> 6;
  float s = wave_sum(lossh);
  if (lane == 0) red[wv] = s;
  __syncthreads();
  if (threadIdx.x == 0) atomicAdd(&accs[5], red[0] + red[1] + red[2] + red[3]);
}

__global__ __launch_bounds__(256) void tail_nomins(
    const float* __restrict__ recon, const float* __restrict__ gt,
    const float* __restrict__ mean, const float* __restrict__ logv,
    float* __restrict__ accs)
{
  __shared__ float red[4][2];
  const int t = blockIdx.x * 256 + threadIdx.x;
  float rsum = 0.f, ksum = 0.f;
  if (t < NB * NH) {
    const float* rp = recon + (size_t)t * 3;
    const float* gp = gt + (size_t)t * 3;
    float d0 = rp[0] - gp[0], d1 = rp[1] - gp[1], d2 = rp[2] - gp[2];
    rsum = d0*d0 + d1*d1 + d2*d2;
  }
  if (t < NB * NZ) {
    float m = mean[t], lv = logv[t];
    ksum = 1.f + lv - m * m - expf(lv);
  }
  float vals[2] = {rsum, ksum};
  const int lane = threadIdx.x & 63, wv = threadIdx.x >> 6;
  for (int q = 0; q < 2; ++q) {
    float s = wave_sum(vals[q]);
    if (lane == 0) red[wv][q] = s;
  }
  __syncthreads();
  if (threadIdx.x < 2) {
    float s = red[0][threadIdx.x] + red[1][threadIdx.x] + red[2][threadIdx.x] + red[3][threadIdx.x];
    atomicAdd(&accs[6 + threadIdx.x], s);
  }
}

__global__ void init_small(float* accs) {
  int t = threadIdx.x;
  if (t < 8) accs[t] = 0.0f;
}

extern "C" void kernel_launch(void* const* d_in, const int* in_sizes, int n_in,
                              void* d_out, int out_size, void* d_ws, size_t ws_size,
                              hipStream_t stream) {
  const float* recon = (const float*)d_in[0];
  const float* gt    = (const float*)d_in[1];
  const float* rnorm = (const float*)d_in[2];
  const float* gnorm = (const float*)d_in[3];
  const float* obj   = (const float*)d_in[4];
  const float* mean  = (const float*)d_in[5];
  const float* logv  = (const float*)d_in[6];
  const float* vw    = (const float*)d_in[7];
  float* out = (float*)d_out;

  float* accs = (float*)d_ws;
  uint32* minH = (uint32*)(accs + 8);                 // 2*NB*NH u32
  ull* packO = (ull*)(minH + N_MINH);                 // 2*NB*NO u64 (8B-aligned)
  const size_t needed = 8 * sizeof(float) + (size_t)N_MINH * 4 + (size_t)N_PACK * 8;

  if (ws_size >= needed) {
    {
      int total = N_PACK;  // largest init extent (192000)
      int blocks = (total + 255) / 256;
      init_kernel<<<blocks, 256, 0, stream>>>(accs, minH, packO);
    }
    mega1<<<NB * OBJ_TILES * 2 + NB * 4 * OC_NUM, 256, 0, stream>>>(
        recon, gt, obj, minH, minH + NB * NH, packO, packO + NB * NO);
    mega2<<<NB * OBJ_TILES + (NB * NH + 255) / 256, 256, 0, stream>>>(
        recon, gt, rnorm, gnorm, obj, mean, logv, vw,
        minH, minH + NB * NH, packO, packO + NB * NO, accs);
    final_kernel<<<1, 1, 0, stream>>>(accs, out);
  } else {
    init_small<<<1, 64, 0, stream>>>(accs);
    obj_mono<<<NB * OBJ_TILES, 256, 0, stream>>>(recon, gt, rnorm, gnorm, obj, accs);
    hand_full<<<NB * 4, 256, 0, stream>>>(recon, gt, obj, vw, accs);
    tail_nomins<<<(NB * NH + 255) / 256, 256, 0, stream>>>(recon, gt, mean, logv, accs);
    final_kernel<<<1, 1, 0, stream>>>(accs, out);
  }
}

// Round 3
// 129.454 us; speedup vs baseline: 1.4895x; 1.0210x over previous
//
#include <hip/hip_runtime.h>
#include <math.h>

// GraspCVAE loss, MI355X — round 3.
// Change vs round 2: register-tile 4 points per lane in every NN inner loop so
// each broadcast ds_read_b128 feeds 24 FMA-class ops (round 2 was LDS-pipe
// bound: 2.39M ds_read_b128 = 47us ~= mega1's whole duration). Also: j-split
// raised to 4 (shorter critical path), mega2's prior loop tiled 4x, and the
// final combine fused into mega2 via atomic-counter last-block-finishes.
// Dispatches: init -> mega1 -> mega2(+final). ws need: 1.74MB (proven).

#define NB 32
#define NH 778
#define NO 3000
#define NZ 64
#define NP 204

#define P_OBJ 4                       // obj pts per lane
#define OBJ_PTS (256 * P_OBJ)         // 1024 obj pts per block
#define OBJ_TILES 3                   // ceil(3000/1024)
#define JSPLIT 4
#define JCH 195                       // ceil(778/4)
#define OC_NUM 12                     // obj chunks, hand side
#define OC_SIZE 250

#define OBJ_BLKS (NB * OBJ_TILES * JSPLIT)   // 384
#define HAND_BLKS (NB * OC_NUM)              // 384
#define FIN_OBJ_BLKS (NB * OBJ_TILES)        // 96
#define FIN_TAIL_BLKS ((NB * NH + 255) / 256) // 98
#define FIN_BLKS (FIN_OBJ_BLKS + FIN_TAIL_BLKS)

typedef unsigned int uint32;
typedef unsigned long long ull;

__device__ __constant__ int c_prior[NP] = {
  697,698,699,700,712,713,714,715,737,738,739,740,741,743,744,745,746,748,749,750,
  753,754,755,756,757,758,759,760,761,762,763,764,765,766,767,768,
  46,47,48,49,164,165,166,167,194,195,223,237,238,280,281,298,301,317,320,323,
  324,325,326,327,328,329,330,331,332,333,340,341,342,343,344,345,346,347,348,349,
  350,351,352,353,354,355,
  356,357,358,359,375,376,386,387,396,397,402,403,413,429,433,434,435,436,437,438,
  439,440,441,442,443,444,452,453,454,455,456,459,460,461,462,463,464,465,466,467,
  468,469,470,471,484,485,486,496,497,506,507,513,514,524,545,546,547,548,549,550,
  551,552,553,555,563,564,565,566,567,570,572,573,574,575,576,577,578,
  580,581,582,583,600,601,602,614,615,624,625,630,631,641,663,664,665,666,667,668,
  670,672,680,681,682,683,684,686,687,688,689,690,691,692,693,694,695,
  73,96,98,99,772,774,775,777
};

__device__ inline float wave_sum(float v) {
  v += __shfl_down(v, 32);
  v += __shfl_down(v, 16);
  v += __shfl_down(v, 8);
  v += __shfl_down(v, 4);
  v += __shfl_down(v, 2);
  v += __shfl_down(v, 1);
  return v;
}

// ws layout: accs[0..7] partial sums, accs[8] = int counter, then minH, then packO
#define N_MINH (2 * NB * NH)          // 49792 u32
#define N_PACK (2 * NB * NO)          // 192000 u64

__global__ void init_kernel(float* accs, uint32* minH, ull* packO) {
  int t = blockIdx.x * blockDim.x + threadIdx.x;
  if (t < 9) accs[t] = 0.0f;          // 8 sums + counter (bit pattern 0)
  if (t < N_MINH) minH[t] = 0x7F800000u;   // +inf
  if (t < N_PACK) packO[t] = ~0ull;
}

// accs: 0 penetr, 1 npts, 2 contact, 3 consist, 4 loss_o, 5 loss_h, 6 recon_sq, 7 kld
__global__ __launch_bounds__(256) void mega1(
    const float* __restrict__ recon, const float* __restrict__ gt,
    const float* __restrict__ obj,
    uint32* __restrict__ minHR, uint32* __restrict__ minHG,
    ull* __restrict__ packR, ull* __restrict__ packG)
{
  const int bid = blockIdx.x;
  const int tid = threadIdx.x;

  if (bid < OBJ_BLKS) {
    // ---- obj -> hand NN: 4 obj pts/lane, j-split 4 ----
    __shared__ float4 sR[JCH];
    __shared__ float4 sG[JCH];
    const int b    = bid / (OBJ_TILES * JSPLIT);
    const int rem  = bid % (OBJ_TILES * JSPLIT);
    const int tile = rem / JSPLIT;
    const int half = rem % JSPLIT;
    const int jbase = half * JCH;
    const int jcnt = (NH - jbase < JCH) ? (NH - jbase) : JCH;  // 195,195,195,193

    for (int i = tid; i < jcnt; i += 256) {
      const float* p = recon + ((size_t)b * NH + jbase + i) * 3;
      float x = p[0], y = p[1], z = p[2];
      sR[i] = make_float4(x, y, z, x*x + y*y + z*z);
      const float* q = gt + ((size_t)b * NH + jbase + i) * 3;
      float gx = q[0], gy = q[1], gz = q[2];
      sG[i] = make_float4(gx, gy, gz, gx*gx + gy*gy + gz*gz);
    }
    __syncthreads();

    float nx[P_OBJ], ny[P_OBJ], nz[P_OBJ], o2v[P_OBJ];
    int ob[P_OBJ]; bool val[P_OBJ];
    #pragma unroll
    for (int m = 0; m < P_OBJ; ++m) {
      int o = tile * OBJ_PTS + m * 256 + tid;
      ob[m] = o; val[m] = (o < NO);
      float x = 0.f, y = 0.f, z = 0.f;
      if (val[m]) {
        const float* op = obj + ((size_t)b * NO + o) * 3;
        x = op[0]; y = op[1]; z = op[2];
      }
      nx[m] = -2.f * x; ny[m] = -2.f * y; nz[m] = -2.f * z;
      o2v[m] = x*x + y*y + z*z;
    }

    float bR[P_OBJ], bG[P_OBJ]; int iR[P_OBJ], iG[P_OBJ];
    #pragma unroll
    for (int m = 0; m < P_OBJ; ++m) { bR[m] = 3.4e38f; bG[m] = 3.4e38f; iR[m] = 0; iG[m] = 0; }

    #pragma unroll 2
    for (int i = 0; i < jcnt; ++i) {
      float4 h = sR[i];
      #pragma unroll
      for (int m = 0; m < P_OBJ; ++m) {
        float t = fmaf(nx[m], h.x, h.w);
        t = fmaf(ny[m], h.y, t);
        t = fmaf(nz[m], h.z, t);
        if (t < bR[m]) { bR[m] = t; iR[m] = jbase + i; }
      }
      float4 g = sG[i];
      #pragma unroll
      for (int m = 0; m < P_OBJ; ++m) {
        float u = fmaf(nx[m], g.x, g.w);
        u = fmaf(ny[m], g.y, u);
        u = fmaf(nz[m], g.z, u);
        if (u < bG[m]) { bG[m] = u; iG[m] = jbase + i; }
      }
    }

    #pragma unroll
    for (int m = 0; m < P_OBJ; ++m) {
      if (!val[m]) continue;
      const size_t base = (size_t)b * NO + ob[m];
      float d2R = fmaxf(bR[m] + o2v[m], 0.f);
      float d2G = fmaxf(bG[m] + o2v[m], 0.f);
      atomicMin(&packR[base], ((ull)__float_as_uint(d2R) << 32) | (uint32)iR[m]);
      atomicMin(&packG[base], ((ull)__float_as_uint(d2G) << 32) | (uint32)iG[m]);
    }
  } else {
    // ---- hand -> obj NN: 4 hand pts/lane, obj chunked 12x ----
    __shared__ float4 sO[OC_SIZE];
    const int bid2 = bid - OBJ_BLKS;
    const int oc = bid2 % OC_NUM;
    const int b  = bid2 / OC_NUM;

    const float* Ob = obj + ((size_t)b * NO + oc * OC_SIZE) * 3;
    for (int i = tid; i < OC_SIZE; i += 256) {
      float x = Ob[3*i], y = Ob[3*i+1], z = Ob[3*i+2];
      sO[i] = make_float4(x, y, z, x*x + y*y + z*z);
    }
    __syncthreads();

    float nrx[4], nry[4], nrz[4], r2v[4];
    float ngx[4], ngy[4], ngz[4], g2v[4];
    bool val[4];
    #pragma unroll
    for (int m = 0; m < 4; ++m) {
      int j = m * 256 + tid;
      val[m] = (j < NH);
      float rx = 0.f, ry = 0.f, rz = 0.f, gx = 0.f, gy = 0.f, gz = 0.f;
      if (val[m]) {
        const float* rp = recon + ((size_t)b * NH + j) * 3;
        const float* gp = gt    + ((size_t)b * NH + j) * 3;
        rx = rp[0]; ry = rp[1]; rz = rp[2];
        gx = gp[0]; gy = gp[1]; gz = gp[2];
      }
      nrx[m] = -2.f*rx; nry[m] = -2.f*ry; nrz[m] = -2.f*rz;
      ngx[m] = -2.f*gx; ngy[m] = -2.f*gy; ngz[m] = -2.f*gz;
      r2v[m] = rx*rx + ry*ry + rz*rz;
      g2v[m] = gx*gx + gy*gy + gz*gz;
    }

    float mR[4], mG[4];
    #pragma unroll
    for (int m = 0; m < 4; ++m) { mR[m] = 3.4e38f; mG[m] = 3.4e38f; }

    #pragma unroll 2
    for (int k = 0; k < OC_SIZE; ++k) {
      float4 o4 = sO[k];
      #pragma unroll
      for (int m = 0; m < 4; ++m) {
        float t = fmaf(nrx[m], o4.x, o4.w);
        t = fmaf(nry[m], o4.y, t);
        t = fmaf(nrz[m], o4.z, t);
        mR[m] = fminf(mR[m], t);
        float u = fmaf(ngx[m], o4.x, o4.w);
        u = fmaf(ngy[m], o4.y, u);
        u = fmaf(ngz[m], o4.z, u);
        mG[m] = fminf(mG[m], u);
      }
    }

    #pragma unroll
    for (int m = 0; m < 4; ++m) {
      if (!val[m]) continue;
      int j = m * 256 + tid;
      const int base = b * NH + j;
      float d2R = fmaxf(mR[m] + r2v[m], 0.f);
      float d2G = fmaxf(mG[m] + g2v[m], 0.f);
      atomicMin(&minHR[base], __float_as_uint(d2R));
      atomicMin(&minHG[base], __float_as_uint(d2G));
    }
  }
}

// mega2: obj finalize (96 blocks, 4 pts/lane) + tail (98 blocks) + fused final
__global__ __launch_bounds__(256) void mega2(
    const float* __restrict__ recon, const float* __restrict__ gt,
    const float* __restrict__ rnorm, const float* __restrict__ gnorm,
    const float* __restrict__ obj,
    const float* __restrict__ mean, const float* __restrict__ logv,
    const float* __restrict__ vw,
    const uint32* __restrict__ minHR, const uint32* __restrict__ minHG,
    const ull* __restrict__ packR, const ull* __restrict__ packG,
    float* __restrict__ accs, float* __restrict__ out)
{
  __shared__ float4 sP[NP];
  __shared__ float red[4][5];
  const int bid = blockIdx.x;
  const int tid = threadIdx.x;
  const int lane = tid & 63, wv = tid >> 6;

  if (bid < FIN_OBJ_BLKS) {
    // ---- obj finalize: prior NN + penetr/contact/consistency/loss_o ----
    const int b = bid / OBJ_TILES;
    const int tile = bid % OBJ_TILES;
    if (tid < NP) {
      int j = c_prior[tid];
      const float* p = recon + ((size_t)b * NH + j) * 3;
      float x = p[0], y = p[1], z = p[2];
      sP[tid] = make_float4(x, y, z, x*x + y*y + z*z);
    }
    __syncthreads();

    float nx[P_OBJ], ny[P_OBJ], nz[P_OBJ], o2v[P_OBJ];
    float oxv[P_OBJ], oyv[P_OBJ], ozv[P_OBJ];
    int ob[P_OBJ]; bool val[P_OBJ];
    #pragma unroll
    for (int m = 0; m < P_OBJ; ++m) {
      int o = tile * OBJ_PTS + m * 256 + tid;
      ob[m] = o; val[m] = (o < NO);
      float x = 0.f, y = 0.f, z = 0.f;
      if (val[m]) {
        const float* op = obj + ((size_t)b * NO + o) * 3;
        x = op[0]; y = op[1]; z = op[2];
      }
      oxv[m] = x; oyv[m] = y; ozv[m] = z;
      nx[m] = -2.f * x; ny[m] = -2.f * y; nz[m] = -2.f * z;
      o2v[m] = x*x + y*y + z*z;
    }

    float bP[P_OBJ];
    #pragma unroll
    for (int m = 0; m < P_OBJ; ++m) bP[m] = 3.4e38f;
    #pragma unroll 2
    for (int k = 0; k < NP; ++k) {
      float4 h = sP[k];
      #pragma unroll
      for (int m = 0; m < P_OBJ; ++m) {
        float t = fmaf(nx[m], h.x, h.w);
        t = fmaf(ny[m], h.y, t);
        t = fmaf(nz[m], h.z, t);
        bP[m] = fminf(bP[m], t);
      }
    }

    float penetr = 0.f, nptsv = 0.f, contactv = 0.f, consistv = 0.f, lossov = 0.f;
    #pragma unroll
    for (int m = 0; m < P_OBJ; ++m) {
      if (!val[m]) continue;
      const size_t base = (size_t)b * NO + ob[m];
      ull pR = packR[base], pG = packG[base];
      float d2R = __uint_as_float((uint32)(pR >> 32));
      float d2G = __uint_as_float((uint32)(pG >> 32));
      int idxR = (int)(uint32)pR, idxG = (int)(uint32)pG;
      float d2P = fmaxf(bP[m] + o2v[m], 0.f);

      const float* hR = recon + ((size_t)b * NH + idxR) * 3;
      const float* nR = rnorm + ((size_t)b * NH + idxR) * 3;
      float dotR = (oxv[m] - hR[0]) * nR[0] + (oyv[m] - hR[1]) * nR[1] + (ozv[m] - hR[2]) * nR[2];
      const float* hG = gt + ((size_t)b * NH + idxG) * 3;
      const float* nG = gnorm + ((size_t)b * NH + idxG) * 3;
      float dotG = (oxv[m] - hG[0]) * nG[0] + (oyv[m] - hG[1]) * nG[1] + (ozv[m] - hG[2]) * nG[2];

      float sgnR = (dotR > 0.f) ? 1.f : ((dotR < 0.f) ? -1.f : 0.f);
      float sgnG = (dotG > 0.f) ? 1.f : ((dotG < 0.f) ? -1.f : 0.f);
      float sR_ = sqrtf(d2R), sG_ = sqrtf(d2G);
      float o2h = sR_ * sgnR, o2hg = sG_ * sgnG;

      bool interior = dotR < 0.f;
      bool cmap = sG_ < 0.005f;
      bool rcmap = sR_ < 0.005f;

      penetr   += interior ? d2R : 0.f;
      nptsv    += cmap ? 1.f : 0.f;
      contactv += cmap ? d2P : 0.f;
      consistv += (cmap && rcmap) ? 1.f : 0.f;
      float w = (o2h < 0.f) ? 1.5f
              : (((o2hg < 0.01f) && (o2hg > -0.005f)) ? 1.f : 0.1f);
      lossov += fabsf(o2h - o2hg) * w;
    }

    float vals[5] = {penetr, nptsv, contactv, consistv, lossov};
    for (int q = 0; q < 5; ++q) {
      float s = wave_sum(vals[q]);
      if (lane == 0) red[wv][q] = s;
    }
    __syncthreads();
    if (tid < 5) {
      float s = red[0][tid] + red[1][tid] + red[2][tid] + red[3][tid];
      atomicAdd(&accs[tid], s);
    }
  } else {
    // ---- tail: loss_h, recon_loss, KLD ----
    const int t = (bid - FIN_OBJ_BLKS) * 256 + tid;
    float lossh = 0.f, rsum = 0.f, ksum = 0.f;
    if (t < NB * NH) {
      const float* rp = recon + (size_t)t * 3;
      const float* gp = gt + (size_t)t * 3;
      float d0 = rp[0] - gp[0], d1 = rp[1] - gp[1], d2 = rp[2] - gp[2];
      rsum = d0*d0 + d1*d1 + d2*d2;
      int j = t % NH;
      float h2o  = sqrtf(__uint_as_float(minHR[t]));
      float h2og = sqrtf(__uint_as_float(minHG[t]));
      lossh = fabsf(h2o - h2og) * powf(vw[j], 0.4f);
    }
    if (t < NB * NZ) {
      float m = mean[t], lv = logv[t];
      ksum = 1.f + lv - m * m - expf(lv);
    }
    float vals[3] = {lossh, rsum, ksum};
    for (int q = 0; q < 3; ++q) {
      float s = wave_sum(vals[q]);
      if (lane == 0) red[wv][q] = s;
    }
    __syncthreads();
    if (tid < 3) {
      float s = red[0][tid] + red[1][tid] + red[2][tid] + red[3][tid];
      atomicAdd(&accs[5 + tid], s);
    }
  }

  // ---- fused final: last block to finish combines ----
  __syncthreads();
  if (tid == 0) {
    __threadfence();
    int* cnt = (int*)(accs + 8);
    int old = atomicAdd(cnt, 1);
    if (old == FIN_BLKS - 1) {
      float a[8];
      for (int q = 0; q < 8; ++q) a[q] = atomicAdd(&accs[q], 0.0f);  // coherent read
      const float recon_loss = a[6] / (float)NB;
      const float kld = -0.5f * a[7] / (float)NB * 10.f;
      const float penetr = 100.f * a[0] / (float)NB;
      const float npts = a[1];
      const float contact = (npts > 0.f) ? (3000.f * a[2] / ((float)NB * npts)) : 0.f;
      const float consistency = -5.f * a[3] / (npts + 0.0001f);
      const float lossh = 35.f * (1.f - 0.005f) * (a[5] / (float)(NB * NH));
      const float losso = 30.f * (1.f - 0.005f) * (a[4] / (float)(NB * NO));
      out[0] = recon_loss + 0.1f * kld + 1000.f * penetr + 10.f * contact
             + 10.f * consistency + lossh + losso;
    }
  }
}

// ================= fallback path (tiny ws) =================
#define FB_TILES 12
__global__ __launch_bounds__(256) void obj_mono(
    const float* __restrict__ recon, const float* __restrict__ gt,
    const float* __restrict__ rnorm, const float* __restrict__ gnorm,
    const float* __restrict__ obj, float* __restrict__ accs)
{
  __shared__ float4 sR[NH];
  __shared__ float4 sG[NH];
  __shared__ float red[4][5];
  const int b = blockIdx.x / FB_TILES;
  const int tile = blockIdx.x % FB_TILES;
  const int tid = threadIdx.x;

  for (int i = tid; i < NH; i += 256) {
    const float* p = recon + ((size_t)b * NH + i) * 3;
    float x = p[0], y = p[1], z = p[2];
    sR[i] = make_float4(x, y, z, x*x + y*y + z*z);
    const float* q = gt + ((size_t)b * NH + i) * 3;
    float gx = q[0], gy = q[1], gz = q[2];
    sG[i] = make_float4(gx, gy, gz, gx*gx + gy*gy + gz*gz);
  }
  __syncthreads();

  const int o = tile * 256 + tid;
  float penetr = 0.f, nptsv = 0.f, contactv = 0.f, consistv = 0.f, lossov = 0.f;
  if (o < NO) {
    const float* op = obj + ((size_t)b * NO + o) * 3;
    const float ox = op[0], oy = op[1], oz = op[2];
    const float nx = -2.f * ox, ny = -2.f * oy, nz = -2.f * oz;
    const float o2 = ox*ox + oy*oy + oz*oz;
    float bR = 3.4e38f, bG = 3.4e38f;
    int iR = 0, iG = 0;
    for (int i = 0; i < NH; ++i) {
      float4 h = sR[i];
      float t = fmaf(nx, h.x, h.w); t = fmaf(ny, h.y, t); t = fmaf(nz, h.z, t);
      if (t < bR) { bR = t; iR = i; }
      float4 g = sG[i];
      float u = fmaf(nx, g.x, g.w); u = fmaf(ny, g.y, u); u = fmaf(nz, g.z, u);
      if (u < bG) { bG = u; iG = i; }
    }
    float bP = 3.4e38f;
    for (int k = 0; k < NP; ++k) {
      float4 h = sR[c_prior[k]];
      float t = fmaf(nx, h.x, h.w); t = fmaf(ny, h.y, t); t = fmaf(nz, h.z, t);
      bP = fminf(bP, t);
    }
    float d2R = fmaxf(bR + o2, 0.f);
    float d2G = fmaxf(bG + o2, 0.f);
    float d2P = fmaxf(bP + o2, 0.f);
    float4 hR = sR[iR];
    const float* nR = rnorm + ((size_t)b * NH + iR) * 3;
    float dotR = (ox - hR.x) * nR[0] + (oy - hR.y) * nR[1] + (oz - hR.z) * nR[2];
    float4 hG = sG[iG];
    const float* nG = gnorm + ((size_t)b * NH + iG) * 3;
    float dotG = (ox - hG.x) * nG[0] + (oy - hG.y) * nG[1] + (oz - hG.z) * nG[2];
    float sgnR = (dotR > 0.f) ? 1.f : ((dotR < 0.f) ? -1.f : 0.f);
    float sgnG = (dotG > 0.f) ? 1.f : ((dotG < 0.f) ? -1.f : 0.f);
    float sR_ = sqrtf(d2R), sG_ = sqrtf(d2G);
    float o2h = sR_ * sgnR, o2hg = sG_ * sgnG;
    bool interior = dotR < 0.f;
    bool cmap = sG_ < 0.005f, rcmap = sR_ < 0.005f;
    penetr = interior ? d2R : 0.f;
    nptsv = cmap ? 1.f : 0.f;
    contactv = cmap ? d2P : 0.f;
    consistv = (cmap && rcmap) ? 1.f : 0.f;
    float w = (o2h < 0.f) ? 1.5f : (((o2hg < 0.01f) && (o2hg > -0.005f)) ? 1.f : 0.1f);
    lossov = fabsf(o2h - o2hg) * w;
  }
  float vals[5] = {penetr, nptsv, contactv, consistv, lossov};
  const int lane = tid & 63, wv = tid >> 6;
  for (int q = 0; q < 5; ++q) {
    float s = wave_sum(vals[q]);
    if (lane == 0) red[wv][q] = s;
  }
  __syncthreads();
  if (tid < 5) {
    float s = red[0][tid] + red[1][tid] + red[2][tid] + red[3][tid];
    atomicAdd(&accs[tid], s);
  }
}

__global__ __launch_bounds__(256) void hand_full(
    const float* __restrict__ recon, const float* __restrict__ gt,
    const float* __restrict__ obj, const float* __restrict__ vw,
    float* __restrict__ accs)
{
  __shared__ float4 sO[500];
  __shared__ float red[4];
  const int b = blockIdx.x >> 2;
  const int j = ((blockIdx.x & 3) << 8) + threadIdx.x;
  const bool valid = j < NH;
  float rx = 0, ry = 0, rz = 0, gx = 0, gy = 0, gz = 0;
  if (valid) {
    const float* rp = recon + ((size_t)b * NH + j) * 3;
    const float* gp = gt + ((size_t)b * NH + j) * 3;
    rx = rp[0]; ry = rp[1]; rz = rp[2];
    gx = gp[0]; gy = gp[1]; gz = gp[2];
  }
  const float nrx = -2.f*rx, nry = -2.f*ry, nrz = -2.f*rz;
  const float ngx = -2.f*gx, ngy = -2.f*gy, ngz = -2.f*gz;
  const float r2 = rx*rx + ry*ry + rz*rz, g2 = gx*gx + gy*gy + gz*gz;
  float mR = 3.4e38f, mG = 3.4e38f;
  for (int oc = 0; oc < 6; ++oc) {
    __syncthreads();
    const float* Ob = obj + ((size_t)b * NO + oc * 500) * 3;
    for (int i = threadIdx.x; i < 500; i += 256) {
      float x = Ob[3*i], y = Ob[3*i+1], z = Ob[3*i+2];
      sO[i] = make_float4(x, y, z, x*x + y*y + z*z);
    }
    __syncthreads();
    if (valid) {
      for (int k = 0; k < 500; ++k) {
        float4 o4 = sO[k];
        float t = fmaf(nrx, o4.x, o4.w); t = fmaf(nry, o4.y, t); t = fmaf(nrz, o4.z, t);
        mR = fminf(mR, t);
        float u = fmaf(ngx, o4.x, o4.w); u = fmaf(ngy, o4.y, u); u = fmaf(ngz, o4.z, u);
        mG = fminf(mG, u);
      }
    }
  }
  float lossh = valid ? fabsf(sqrtf(fmaxf(mR + r2, 0.f)) - sqrtf(fmaxf(mG + g2, 0.f)))
                        * powf(vw[j], 0.4f) : 0.f;
  const int lane = threadIdx.x & 63, wv = threadIdx.x >> 6;
  float s = wave_sum(lossh);
  if (lane == 0) red[wv] = s;
  __syncthreads();
  if (threadIdx.x == 0) atomicAdd(&accs[5], red[0] + red[1] + red[2] + red[3]);
}

__global__ __launch_bounds__(256) void tail_nomins(
    const float* __restrict__ recon, const float* __restrict__ gt,
    const float* __restrict__ mean, const float* __restrict__ logv,
    float* __restrict__ accs)
{
  __shared__ float red[4][2];
  const int t = blockIdx.x * 256 + threadIdx.x;
  float rsum = 0.f, ksum = 0.f;
  if (t < NB * NH) {
    const float* rp = recon + (size_t)t * 3;
    const float* gp = gt + (size_t)t * 3;
    float d0 = rp[0] - gp[0], d1 = rp[1] - gp[1], d2 = rp[2] - gp[2];
    rsum = d0*d0 + d1*d1 + d2*d2;
  }
  if (t < NB * NZ) {
    float m = mean[t], lv = logv[t];
    ksum = 1.f + lv - m * m - expf(lv);
  }
  float vals[2] = {rsum, ksum};
  const int lane = threadIdx.x & 63, wv = threadIdx.x >> 6;
  for (int q = 0; q < 2; ++q) {
    float s = wave_sum(vals[q]);
    if (lane == 0) red[wv][q] = s;
  }
  __syncthreads();
  if (threadIdx.x < 2) {
    float s = red[0][threadIdx.x] + red[1][threadIdx.x] + red[2][threadIdx.x] + red[3][threadIdx.x];
    atomicAdd(&accs[6 + threadIdx.x], s);
  }
}

__global__ void init_small(float* accs) {
  int t = threadIdx.x;
  if (t < 8) accs[t] = 0.0f;
}

__global__ void final_fb(const float* __restrict__ a, float* __restrict__ out) {
  const float recon_loss = a[6] / (float)NB;
  const float kld = -0.5f * a[7] / (float)NB * 10.f;
  const float penetr = 100.f * a[0] / (float)NB;
  const float npts = a[1];
  const float contact = (npts > 0.f) ? (3000.f * a[2] / ((float)NB * npts)) : 0.f;
  const float consistency = -5.f * a[3] / (npts + 0.0001f);
  const float lossh = 35.f * (1.f - 0.005f) * (a[5] / (float)(NB * NH));
  const float losso = 30.f * (1.f - 0.005f) * (a[4] / (float)(NB * NO));
  out[0] = recon_loss + 0.1f * kld + 1000.f * penetr + 10.f * contact
         + 10.f * consistency + lossh + losso;
}

extern "C" void kernel_launch(void* const* d_in, const int* in_sizes, int n_in,
                              void* d_out, int out_size, void* d_ws, size_t ws_size,
                              hipStream_t stream) {
  const float* recon = (const float*)d_in[0];
  const float* gt    = (const float*)d_in[1];
  const float* rnorm = (const float*)d_in[2];
  const float* gnorm = (const float*)d_in[3];
  const float* obj   = (const float*)d_in[4];
  const float* mean  = (const float*)d_in[5];
  const float* logv  = (const float*)d_in[6];
  const float* vw    = (const float*)d_in[7];
  float* out = (float*)d_out;

  float* accs = (float*)d_ws;                          // 16 floats (8 sums + counter + pad)
  uint32* minH = (uint32*)(accs + 16);                 // 2*NB*NH u32
  ull* packO = (ull*)(minH + N_MINH);                  // 2*NB*NO u64
  const size_t needed = 16 * sizeof(float) + (size_t)N_MINH * 4 + (size_t)N_PACK * 8;

  if (ws_size >= needed) {
    {
      int blocks = (N_PACK + 255) / 256;   // covers all init extents
      init_kernel<<<blocks, 256, 0, stream>>>(accs, minH, packO);
    }
    mega1<<<OBJ_BLKS + HAND_BLKS, 256, 0, stream>>>(
        recon, gt, obj, minH, minH + NB * NH, packO, packO + NB * NO);
    mega2<<<FIN_BLKS, 256, 0, stream>>>(
        recon, gt, rnorm, gnorm, obj, mean, logv, vw,
        minH, minH + NB * NH, packO, packO + NB * NO, accs, out);
  } else {
    init_small<<<1, 64, 0, stream>>>(accs);
    obj_mono<<<NB * FB_TILES, 256, 0, stream>>>(recon, gt, rnorm, gnorm, obj, accs);
    hand_full<<<NB * 4, 256, 0, stream>>>(recon, gt, obj, vw, accs);
    tail_nomins<<<(NB * NH + 255) / 256, 256, 0, stream>>>(recon, gt, mean, logv, accs);
    final_fb<<<1, 1, 0, stream>>>(accs, out);
  }
}

// Round 4
// 123.717 us; speedup vs baseline: 1.5586x; 1.0464x over previous
//
#include <hip/hip_runtime.h>
#include <math.h>

// GraspCVAE loss, MI355X — round 4.
// vs round 3:
//  * obj-side argmin packs index into low 10 mantissa bits of the score
//    (t = |h|^2 - 2 o.h, monotone in d2): inner loop = 3 FMA + and/or + min
//    instead of cmp + 2 cndmask. Candidates paired so fminf(fminf(a,b),acc)
//    can fuse to v_min3_f32.
//  * no atomics / no +inf init: each j-split (obj side, 4) and obj-chunk
//    (hand side, 12) writes partial mins to its own ws slice; mega2 reduces.
//  * 2 dispatches: mega1 (block 0 zeroes accs) -> mega2 (fused final via
//    atomic counter last-block-finishes).
//  * mega2 obj-finalize at 384 blocks (P=1) for gather latency hiding.
// Fallbacks: PATH B = round-3 atomic path (ws >= 1.74MB), PATH C = tiny-ws.

#define NB 32
#define NH 778
#define NO 3000
#define NZ 64
#define NP 204

// ---- PATH A geometry ----
#define P_OBJ 4
#define OBJ_PTS (256 * P_OBJ)        // 1024
#define OBJ_TILES 3                  // ceil(3000/1024)
#define JSPLIT 4
#define JCH 195                      // ceil(778/4)
#define HC 12                        // hand-side obj chunks
#define HCS 250                      // 3000/12
#define OBJ_BLKS (NB * OBJ_TILES * JSPLIT)    // 384
#define HAND_BLKS (NB * HC)                   // 384
#define T2 12                        // mega2 obj tiles (256 pts)
#define FIN_OBJ_BLKS (NB * T2)                // 384
#define FIN_TAIL_BLKS ((NB * NH + 255) / 256) // 98
#define FIN_BLKS (FIN_OBJ_BLKS + FIN_TAIL_BLKS)

#define NKEY (NB * NO)               // 96000 per split-array
#define NHT  (NB * NH)               // 24896 per chunk-array

typedef unsigned int uint32;
typedef unsigned long long ull;

__device__ __constant__ int c_prior[NP] = {
  697,698,699,700,712,713,714,715,737,738,739,740,741,743,744,745,746,748,749,750,
  753,754,755,756,757,758,759,760,761,762,763,764,765,766,767,768,
  46,47,48,49,164,165,166,167,194,195,223,237,238,280,281,298,301,317,320,323,
  324,325,326,327,328,329,330,331,332,333,340,341,342,343,344,345,346,347,348,349,
  350,351,352,353,354,355,
  356,357,358,359,375,376,386,387,396,397,402,403,413,429,433,434,435,436,437,438,
  439,440,441,442,443,444,452,453,454,455,456,459,460,461,462,463,464,465,466,467,
  468,469,470,471,484,485,486,496,497,506,507,513,514,524,545,546,547,548,549,550,
  551,552,553,555,563,564,565,566,567,570,572,573,574,575,576,577,578,
  580,581,582,583,600,601,602,614,615,624,625,630,631,641,663,664,665,666,667,668,
  670,672,680,681,682,683,684,686,687,688,689,690,691,692,693,694,695,
  73,96,98,99,772,774,775,777
};

__device__ inline float wave_sum(float v) {
  v += __shfl_down(v, 32);
  v += __shfl_down(v, 16);
  v += __shfl_down(v, 8);
  v += __shfl_down(v, 4);
  v += __shfl_down(v, 2);
  v += __shfl_down(v, 1);
  return v;
}

// pack candidate index into low 10 mantissa bits; float ordering ~ (t, j)
__device__ inline float packkey(float t, int j) {
  return __uint_as_float((__float_as_uint(t) & 0xFFFFFC00u) | (uint32)j);
}

// =========================== PATH A ===========================
// ws: accs[16] | keyR[4][96000] | keyG[4][96000] | minHR[12][24896] | minHG[12][24896]

// accs: 0 penetr, 1 npts, 2 contact, 3 consist, 4 loss_o, 5 loss_h, 6 recon_sq, 7 kld, 8 counter
__global__ __launch_bounds__(256) void mega1a(
    const float* __restrict__ recon, const float* __restrict__ gt,
    const float* __restrict__ obj,
    float* __restrict__ keyR, float* __restrict__ keyG,
    float* __restrict__ minHR, float* __restrict__ minHG,
    float* __restrict__ accs)
{
  const int bid = blockIdx.x;
  const int tid = threadIdx.x;

  if (bid == 0 && tid < 16) accs[tid] = 0.0f;   // mega2 consumes after kernel boundary

  if (bid < OBJ_BLKS) {
    // ---- obj -> hand NN, j-split 4, packed-index keys, plain stores ----
    __shared__ float4 sR[JCH];
    __shared__ float4 sG[JCH];
    const int b     = bid / (OBJ_TILES * JSPLIT);
    const int rem   = bid % (OBJ_TILES * JSPLIT);
    const int tile  = rem / JSPLIT;
    const int split = rem % JSPLIT;
    const int jbase = split * JCH;
    const int jcnt  = (NH - jbase < JCH) ? (NH - jbase) : JCH;

    for (int i = tid; i < jcnt; i += 256) {
      const float* p = recon + ((size_t)b * NH + jbase + i) * 3;
      float x = p[0], y = p[1], z = p[2];
      sR[i] = make_float4(x, y, z, x*x + y*y + z*z);
      const float* q = gt + ((size_t)b * NH + jbase + i) * 3;
      float gx = q[0], gy = q[1], gz = q[2];
      sG[i] = make_float4(gx, gy, gz, gx*gx + gy*gy + gz*gz);
    }
    __syncthreads();

    float nx[P_OBJ], ny[P_OBJ], nz[P_OBJ];
    int ob[P_OBJ]; bool val[P_OBJ];
    #pragma unroll
    for (int m = 0; m < P_OBJ; ++m) {
      int o = tile * OBJ_PTS + m * 256 + tid;
      ob[m] = o; val[m] = (o < NO);
      float x = 0.f, y = 0.f, z = 0.f;
      if (val[m]) {
        const float* op = obj + ((size_t)b * NO + o) * 3;
        x = op[0]; y = op[1]; z = op[2];
      }
      nx[m] = -2.f * x; ny[m] = -2.f * y; nz[m] = -2.f * z;
    }

    float bR[P_OBJ], bG[P_OBJ];
    #pragma unroll
    for (int m = 0; m < P_OBJ; ++m) { bR[m] = 3.4e38f; bG[m] = 3.4e38f; }

    int i = 0;
    for (; i + 1 < jcnt; i += 2) {
      float4 h0 = sR[i], h1 = sR[i + 1];
      #pragma unroll
      for (int m = 0; m < P_OBJ; ++m) {
        float t0 = fmaf(nx[m], h0.x, h0.w); t0 = fmaf(ny[m], h0.y, t0); t0 = fmaf(nz[m], h0.z, t0);
        float t1 = fmaf(nx[m], h1.x, h1.w); t1 = fmaf(ny[m], h1.y, t1); t1 = fmaf(nz[m], h1.z, t1);
        bR[m] = fminf(bR[m], fminf(packkey(t0, jbase + i), packkey(t1, jbase + i + 1)));
      }
      float4 g0 = sG[i], g1 = sG[i + 1];
      #pragma unroll
      for (int m = 0; m < P_OBJ; ++m) {
        float t0 = fmaf(nx[m], g0.x, g0.w); t0 = fmaf(ny[m], g0.y, t0); t0 = fmaf(nz[m], g0.z, t0);
        float t1 = fmaf(nx[m], g1.x, g1.w); t1 = fmaf(ny[m], g1.y, t1); t1 = fmaf(nz[m], g1.z, t1);
        bG[m] = fminf(bG[m], fminf(packkey(t0, jbase + i), packkey(t1, jbase + i + 1)));
      }
    }
    if (i < jcnt) {
      float4 h0 = sR[i];
      float4 g0 = sG[i];
      #pragma unroll
      for (int m = 0; m < P_OBJ; ++m) {
        float t0 = fmaf(nx[m], h0.x, h0.w); t0 = fmaf(ny[m], h0.y, t0); t0 = fmaf(nz[m], h0.z, t0);
        bR[m] = fminf(bR[m], packkey(t0, jbase + i));
        float u0 = fmaf(nx[m], g0.x, g0.w); u0 = fmaf(ny[m], g0.y, u0); u0 = fmaf(nz[m], g0.z, u0);
        bG[m] = fminf(bG[m], packkey(u0, jbase + i));
      }
    }

    #pragma unroll
    for (int m = 0; m < P_OBJ; ++m) {
      if (!val[m]) continue;
      const size_t idx = (size_t)split * NKEY + (size_t)b * NO + ob[m];
      keyR[idx] = bR[m];
      keyG[idx] = bG[m];
    }
  } else {
    // ---- hand -> obj NN, 12 chunks, per-chunk t-min (d2 = t + |h|^2 later) ----
    __shared__ float4 sO[HCS];
    const int bid2 = bid - OBJ_BLKS;
    const int oc = bid2 % HC;
    const int b  = bid2 / HC;

    const float* Ob = obj + ((size_t)b * NO + oc * HCS) * 3;
    for (int i2 = tid; i2 < HCS; i2 += 256) {
      float x = Ob[3*i2], y = Ob[3*i2+1], z = Ob[3*i2+2];
      sO[i2] = make_float4(x, y, z, x*x + y*y + z*z);
    }
    __syncthreads();

    float nrx[4], nry[4], nrz[4];
    float ngx[4], ngy[4], ngz[4];
    bool val[4];
    #pragma unroll
    for (int m = 0; m < 4; ++m) {
      int j = m * 256 + tid;
      val[m] = (j < NH);
      float rx = 0.f, ry = 0.f, rz = 0.f, gx = 0.f, gy = 0.f, gz = 0.f;
      if (val[m]) {
        const float* rp = recon + ((size_t)b * NH + j) * 3;
        const float* gp = gt    + ((size_t)b * NH + j) * 3;
        rx = rp[0]; ry = rp[1]; rz = rp[2];
        gx = gp[0]; gy = gp[1]; gz = gp[2];
      }
      nrx[m] = -2.f*rx; nry[m] = -2.f*ry; nrz[m] = -2.f*rz;
      ngx[m] = -2.f*gx; ngy[m] = -2.f*gy; ngz[m] = -2.f*gz;
    }

    float mR[4], mG[4];
    #pragma unroll
    for (int m = 0; m < 4; ++m) { mR[m] = 3.4e38f; mG[m] = 3.4e38f; }

    for (int k = 0; k < HCS; k += 2) {
      float4 o0 = sO[k], o1 = sO[k + 1];
      #pragma unroll
      for (int m = 0; m < 4; ++m) {
        float t0 = fmaf(nrx[m], o0.x, o0.w); t0 = fmaf(nry[m], o0.y, t0); t0 = fmaf(nrz[m], o0.z, t0);
        float t1 = fmaf(nrx[m], o1.x, o1.w); t1 = fmaf(nry[m], o1.y, t1); t1 = fmaf(nrz[m], o1.z, t1);
        mR[m] = fminf(mR[m], fminf(t0, t1));
        float u0 = fmaf(ngx[m], o0.x, o0.w); u0 = fmaf(ngy[m], o0.y, u0); u0 = fmaf(ngz[m], o0.z, u0);
        float u1 = fmaf(ngx[m], o1.x, o1.w); u1 = fmaf(ngy[m], o1.y, u1); u1 = fmaf(ngz[m], o1.z, u1);
        mG[m] = fminf(mG[m], fminf(u0, u1));
      }
    }

    #pragma unroll
    for (int m = 0; m < 4; ++m) {
      if (!val[m]) continue;
      int j = m * 256 + tid;
      const size_t idx = (size_t)oc * NHT + (size_t)b * NH + j;
      minHR[idx] = mR[m];
      minHG[idx] = mG[m];
    }
  }
}

__global__ __launch_bounds__(256) void mega2a(
    const float* __restrict__ recon, const float* __restrict__ gt,
    const float* __restrict__ rnorm, const float* __restrict__ gnorm,
    const float* __restrict__ obj,
    const float* __restrict__ mean, const float* __restrict__ logv,
    const float* __restrict__ vw,
    const float* __restrict__ keyR, const float* __restrict__ keyG,
    const float* __restrict__ minHR, const float* __restrict__ minHG,
    float* __restrict__ accs, float* __restrict__ out)
{
  __shared__ float4 sP[NP];
  __shared__ float red[4][5];
  const int bid = blockIdx.x;
  const int tid = threadIdx.x;
  const int lane = tid & 63, wv = tid >> 6;

  if (bid < FIN_OBJ_BLKS) {
    // ---- obj finalize: reduce split keys, prior NN, flags/partials ----
    const int b = bid / T2;
    const int tile = bid % T2;
    if (tid < NP) {
      int j = c_prior[tid];
      const float* p = recon + ((size_t)b * NH + j) * 3;
      float x = p[0], y = p[1], z = p[2];
      sP[tid] = make_float4(x, y, z, x*x + y*y + z*z);
    }
    __syncthreads();

    const int o = tile * 256 + tid;
    float penetr = 0.f, nptsv = 0.f, contactv = 0.f, consistv = 0.f, lossov = 0.f;
    if (o < NO) {
      const float* op = obj + ((size_t)b * NO + o) * 3;
      const float ox = op[0], oy = op[1], oz = op[2];
      const float nx = -2.f * ox, ny = -2.f * oy, nz = -2.f * oz;
      const float o2 = ox*ox + oy*oy + oz*oz;
      const size_t base = (size_t)b * NO + o;

      float kR = 3.4e38f, kG = 3.4e38f;
      #pragma unroll
      for (int s = 0; s < JSPLIT; ++s) {
        kR = fminf(kR, keyR[(size_t)s * NKEY + base]);
        kG = fminf(kG, keyG[(size_t)s * NKEY + base]);
      }
      uint32 kRb = __float_as_uint(kR), kGb = __float_as_uint(kG);
      int idxR = (int)(kRb & 0x3FFu), idxG = (int)(kGb & 0x3FFu);
      float d2R = fmaxf(__uint_as_float(kRb & 0xFFFFFC00u) + o2, 0.f);
      float d2G = fmaxf(__uint_as_float(kGb & 0xFFFFFC00u) + o2, 0.f);

      float bP = 3.4e38f;
      for (int k = 0; k < NP; k += 2) {
        float4 h0 = sP[k], h1 = sP[k + 1];
        float t0 = fmaf(nx, h0.x, h0.w); t0 = fmaf(ny, h0.y, t0); t0 = fmaf(nz, h0.z, t0);
        float t1 = fmaf(nx, h1.x, h1.w); t1 = fmaf(ny, h1.y, t1); t1 = fmaf(nz, h1.z, t1);
        bP = fminf(bP, fminf(t0, t1));
      }
      float d2P = fmaxf(bP + o2, 0.f);

      const float* hR = recon + ((size_t)b * NH + idxR) * 3;
      const float* nR = rnorm + ((size_t)b * NH + idxR) * 3;
      float dotR = (ox - hR[0]) * nR[0] + (oy - hR[1]) * nR[1] + (oz - hR[2]) * nR[2];
      const float* hG = gt + ((size_t)b * NH + idxG) * 3;
      const float* nG = gnorm + ((size_t)b * NH + idxG) * 3;
      float dotG = (ox - hG[0]) * nG[0] + (oy - hG[1]) * nG[1] + (oz - hG[2]) * nG[2];

      float sgnR = (dotR > 0.f) ? 1.f : ((dotR < 0.f) ? -1.f : 0.f);
      float sgnG = (dotG > 0.f) ? 1.f : ((dotG < 0.f) ? -1.f : 0.f);
      float sR_ = sqrtf(d2R), sG_ = sqrtf(d2G);
      float o2h = sR_ * sgnR, o2hg = sG_ * sgnG;

      bool interior = dotR < 0.f;
      bool cmap = sG_ < 0.005f;
      bool rcmap = sR_ < 0.005f;

      penetr   = interior ? d2R : 0.f;
      nptsv    = cmap ? 1.f : 0.f;
      contactv = cmap ? d2P : 0.f;
      consistv = (cmap && rcmap) ? 1.f : 0.f;
      float w = (o2h < 0.f) ? 1.5f
              : (((o2hg < 0.01f) && (o2hg > -0.005f)) ? 1.f : 0.1f);
      lossov = fabsf(o2h - o2hg) * w;
    }

    float vals[5] = {penetr, nptsv, contactv, consistv, lossov};
    for (int q = 0; q < 5; ++q) {
      float s = wave_sum(vals[q]);
      if (lane == 0) red[wv][q] = s;
    }
    __syncthreads();
    if (tid < 5) {
      float s = red[0][tid] + red[1][tid] + red[2][tid] + red[3][tid];
      atomicAdd(&accs[tid], s);
    }
  } else {
    // ---- tail: reduce hand-chunk mins, loss_h, recon_loss, KLD ----
    const int t = (bid - FIN_OBJ_BLKS) * 256 + tid;
    float lossh = 0.f, rsum = 0.f, ksum = 0.f;
    if (t < NB * NH) {
      const float* rp = recon + (size_t)t * 3;
      const float* gp = gt + (size_t)t * 3;
      float rx = rp[0], ry = rp[1], rz = rp[2];
      float gx = gp[0], gy = gp[1], gz = gp[2];
      float d0 = rx - gx, d1 = ry - gy, d2 = rz - gz;
      rsum = d0*d0 + d1*d1 + d2*d2;

      float mRt = 3.4e38f, mGt = 3.4e38f;
      #pragma unroll
      for (int c = 0; c < HC; ++c) {
        mRt = fminf(mRt, minHR[(size_t)c * NHT + t]);
        mGt = fminf(mGt, minHG[(size_t)c * NHT + t]);
      }
      float r2 = rx*rx + ry*ry + rz*rz;
      float g2 = gx*gx + gy*gy + gz*gz;
      float d2Rh = fmaxf(mRt + r2, 0.f);
      float d2Gh = fmaxf(mGt + g2, 0.f);
      int j = t % NH;
      lossh = fabsf(sqrtf(d2Rh) - sqrtf(d2Gh)) * powf(vw[j], 0.4f);
    }
    if (t < NB * NZ) {
      float m = mean[t], lv = logv[t];
      ksum = 1.f + lv - m * m - expf(lv);
    }
    float vals[3] = {lossh, rsum, ksum};
    for (int q = 0; q < 3; ++q) {
      float s = wave_sum(vals[q]);
      if (lane == 0) red[wv][q] = s;
    }
    __syncthreads();
    if (tid < 3) {
      float s = red[0][tid] + red[1][tid] + red[2][tid] + red[3][tid];
      atomicAdd(&accs[5 + tid], s);
    }
  }

  // ---- fused final: last block combines ----
  __syncthreads();
  if (tid == 0) {
    __threadfence();
    int* cnt = (int*)(accs + 8);
    int old = atomicAdd(cnt, 1);
    if (old == FIN_BLKS - 1) {
      float a[8];
      for (int q = 0; q < 8; ++q) a[q] = atomicAdd(&accs[q], 0.0f);
      const float recon_loss = a[6] / (float)NB;
      const float kld = -0.5f * a[7] / (float)NB * 10.f;
      const float penetr = 100.f * a[0] / (float)NB;
      const float npts = a[1];
      const float contact = (npts > 0.f) ? (3000.f * a[2] / ((float)NB * npts)) : 0.f;
      const float consistency = -5.f * a[3] / (npts + 0.0001f);
      const float lossh = 35.f * (1.f - 0.005f) * (a[5] / (float)(NB * NH));
      const float losso = 30.f * (1.f - 0.005f) * (a[4] / (float)(NB * NO));
      out[0] = recon_loss + 0.1f * kld + 1000.f * penetr + 10.f * contact
             + 10.f * consistency + lossh + losso;
    }
  }
}

// =========================== PATH B (round-3 atomic path) ===========================
#define B_OBJ_TILES 3
#define B_JSPLIT 4
#define B_JCH 195
#define B_OC_NUM 12
#define B_OC_SIZE 250
#define B_OBJ_BLKS (NB * B_OBJ_TILES * B_JSPLIT)
#define B_HAND_BLKS (NB * B_OC_NUM)
#define B_FIN_OBJ (NB * B_OBJ_TILES)
#define B_FIN_TAIL ((NB * NH + 255) / 256)
#define B_FIN (B_FIN_OBJ + B_FIN_TAIL)
#define N_MINH (2 * NB * NH)
#define N_PACK (2 * NB * NO)

__global__ void init_b(float* accs, uint32* minH, ull* packO) {
  int t = blockIdx.x * blockDim.x + threadIdx.x;
  if (t < 9) accs[t] = 0.0f;
  if (t < N_MINH) minH[t] = 0x7F800000u;
  if (t < N_PACK) packO[t] = ~0ull;
}

__global__ __launch_bounds__(256) void mega1b(
    const float* __restrict__ recon, const float* __restrict__ gt,
    const float* __restrict__ obj,
    uint32* __restrict__ minHRb, uint32* __restrict__ minHGb,
    ull* __restrict__ packR, ull* __restrict__ packG)
{
  const int bid = blockIdx.x;
  const int tid = threadIdx.x;
  if (bid < B_OBJ_BLKS) {
    __shared__ float4 sR[B_JCH];
    __shared__ float4 sG[B_JCH];
    const int b    = bid / (B_OBJ_TILES * B_JSPLIT);
    const int rem  = bid % (B_OBJ_TILES * B_JSPLIT);
    const int tile = rem / B_JSPLIT;
    const int half = rem % B_JSPLIT;
    const int jbase = half * B_JCH;
    const int jcnt = (NH - jbase < B_JCH) ? (NH - jbase) : B_JCH;
    for (int i = tid; i < jcnt; i += 256) {
      const float* p = recon + ((size_t)b * NH + jbase + i) * 3;
      float x = p[0], y = p[1], z = p[2];
      sR[i] = make_float4(x, y, z, x*x + y*y + z*z);
      const float* q = gt + ((size_t)b * NH + jbase + i) * 3;
      float gx = q[0], gy = q[1], gz = q[2];
      sG[i] = make_float4(gx, gy, gz, gx*gx + gy*gy + gz*gz);
    }
    __syncthreads();
    float nx[4], ny[4], nz[4], o2v[4]; int ob[4]; bool val[4];
    #pragma unroll
    for (int m = 0; m < 4; ++m) {
      int o = tile * 1024 + m * 256 + tid;
      ob[m] = o; val[m] = (o < NO);
      float x = 0.f, y = 0.f, z = 0.f;
      if (val[m]) { const float* op = obj + ((size_t)b * NO + o) * 3; x = op[0]; y = op[1]; z = op[2]; }
      nx[m] = -2.f*x; ny[m] = -2.f*y; nz[m] = -2.f*z; o2v[m] = x*x + y*y + z*z;
    }
    float bR[4], bG[4]; int iR[4], iG[4];
    #pragma unroll
    for (int m = 0; m < 4; ++m) { bR[m] = 3.4e38f; bG[m] = 3.4e38f; iR[m] = 0; iG[m] = 0; }
    for (int i = 0; i < jcnt; ++i) {
      float4 h = sR[i];
      #pragma unroll
      for (int m = 0; m < 4; ++m) {
        float t = fmaf(nx[m], h.x, h.w); t = fmaf(ny[m], h.y, t); t = fmaf(nz[m], h.z, t);
        if (t < bR[m]) { bR[m] = t; iR[m] = jbase + i; }
      }
      float4 g = sG[i];
      #pragma unroll
      for (int m = 0; m < 4; ++m) {
        float u = fmaf(nx[m], g.x, g.w); u = fmaf(ny[m], g.y, u); u = fmaf(nz[m], g.z, u);
        if (u < bG[m]) { bG[m] = u; iG[m] = jbase + i; }
      }
    }
    #pragma unroll
    for (int m = 0; m < 4; ++m) {
      if (!val[m]) continue;
      const size_t base = (size_t)b * NO + ob[m];
      float d2R = fmaxf(bR[m] + o2v[m], 0.f);
      float d2G = fmaxf(bG[m] + o2v[m], 0.f);
      atomicMin(&packR[base], ((ull)__float_as_uint(d2R) << 32) | (uint32)iR[m]);
      atomicMin(&packG[base], ((ull)__float_as_uint(d2G) << 32) | (uint32)iG[m]);
    }
  } else {
    __shared__ float4 sO[B_OC_SIZE];
    const int bid2 = bid - B_OBJ_BLKS;
    const int oc = bid2 % B_OC_NUM;
    const int b  = bid2 / B_OC_NUM;
    const float* Ob = obj + ((size_t)b * NO + oc * B_OC_SIZE) * 3;
    for (int i = tid; i < B_OC_SIZE; i += 256) {
      float x = Ob[3*i], y = Ob[3*i+1], z = Ob[3*i+2];
      sO[i] = make_float4(x, y, z, x*x + y*y + z*z);
    }
    __syncthreads();
    float nrx[4], nry[4], nrz[4], r2v[4], ngx[4], ngy[4], ngz[4], g2v[4]; bool val[4];
    #pragma unroll
    for (int m = 0; m < 4; ++m) {
      int j = m * 256 + tid; val[m] = (j < NH);
      float rx=0,ry=0,rz=0,gx=0,gy=0,gz=0;
      if (val[m]) {
        const float* rp = recon + ((size_t)b * NH + j) * 3;
        const float* gp = gt    + ((size_t)b * NH + j) * 3;
        rx=rp[0];ry=rp[1];rz=rp[2]; gx=gp[0];gy=gp[1];gz=gp[2];
      }
      nrx[m]=-2.f*rx;nry[m]=-2.f*ry;nrz[m]=-2.f*rz;
      ngx[m]=-2.f*gx;ngy[m]=-2.f*gy;ngz[m]=-2.f*gz;
      r2v[m]=rx*rx+ry*ry+rz*rz; g2v[m]=gx*gx+gy*gy+gz*gz;
    }
    float mR[4], mG[4];
    #pragma unroll
    for (int m = 0; m < 4; ++m) { mR[m]=3.4e38f; mG[m]=3.4e38f; }
    for (int k = 0; k < B_OC_SIZE; ++k) {
      float4 o4 = sO[k];
      #pragma unroll
      for (int m = 0; m < 4; ++m) {
        float t = fmaf(nrx[m], o4.x, o4.w); t = fmaf(nry[m], o4.y, t); t = fmaf(nrz[m], o4.z, t);
        mR[m] = fminf(mR[m], t);
        float u = fmaf(ngx[m], o4.x, o4.w); u = fmaf(ngy[m], o4.y, u); u = fmaf(ngz[m], o4.z, u);
        mG[m] = fminf(mG[m], u);
      }
    }
    #pragma unroll
    for (int m = 0; m < 4; ++m) {
      if (!val[m]) continue;
      int j = m * 256 + tid;
      const int base = b * NH + j;
      atomicMin(&minHRb[base], __float_as_uint(fmaxf(mR[m] + r2v[m], 0.f)));
      atomicMin(&minHGb[base], __float_as_uint(fmaxf(mG[m] + g2v[m], 0.f)));
    }
  }
}

__global__ __launch_bounds__(256) void mega2b(
    const float* __restrict__ recon, const float* __restrict__ gt,
    const float* __restrict__ rnorm, const float* __restrict__ gnorm,
    const float* __restrict__ obj,
    const float* __restrict__ mean, const float* __restrict__ logv,
    const float* __restrict__ vw,
    const uint32* __restrict__ minHRb, const uint32* __restrict__ minHGb,
    const ull* __restrict__ packR, const ull* __restrict__ packG,
    float* __restrict__ accs, float* __restrict__ out)
{
  __shared__ float4 sP[NP];
  __shared__ float red[4][5];
  const int bid = blockIdx.x;
  const int tid = threadIdx.x;
  const int lane = tid & 63, wv = tid >> 6;

  if (bid < B_FIN_OBJ) {
    const int b = bid / B_OBJ_TILES;
    const int tile = bid % B_OBJ_TILES;
    if (tid < NP) {
      int j = c_prior[tid];
      const float* p = recon + ((size_t)b * NH + j) * 3;
      float x = p[0], y = p[1], z = p[2];
      sP[tid] = make_float4(x, y, z, x*x + y*y + z*z);
    }
    __syncthreads();
    float penetr=0.f, nptsv=0.f, contactv=0.f, consistv=0.f, lossov=0.f;
    #pragma unroll
    for (int m = 0; m < 4; ++m) {
      int o = tile * 1024 + m * 256 + tid;
      if (o >= NO) continue;
      const float* op = obj + ((size_t)b * NO + o) * 3;
      float ox = op[0], oy = op[1], oz = op[2];
      float nx = -2.f*ox, ny = -2.f*oy, nz = -2.f*oz;
      float o2 = ox*ox + oy*oy + oz*oz;
      const size_t base = (size_t)b * NO + o;
      ull pR = packR[base], pG = packG[base];
      float d2R = __uint_as_float((uint32)(pR >> 32));
      float d2G = __uint_as_float((uint32)(pG >> 32));
      int idxR = (int)(uint32)pR, idxG = (int)(uint32)pG;
      float bP = 3.4e38f;
      for (int k = 0; k < NP; ++k) {
        float4 h = sP[k];
        float t = fmaf(nx, h.x, h.w); t = fmaf(ny, h.y, t); t = fmaf(nz, h.z, t);
        bP = fminf(bP, t);
      }
      float d2P = fmaxf(bP + o2, 0.f);
      const float* hR = recon + ((size_t)b * NH + idxR) * 3;
      const float* nR = rnorm + ((size_t)b * NH + idxR) * 3;
      float dotR = (ox-hR[0])*nR[0] + (oy-hR[1])*nR[1] + (oz-hR[2])*nR[2];
      const float* hG = gt + ((size_t)b * NH + idxG) * 3;
      const float* nG = gnorm + ((size_t)b * NH + idxG) * 3;
      float dotG = (ox-hG[0])*nG[0] + (oy-hG[1])*nG[1] + (oz-hG[2])*nG[2];
      float sgnR = (dotR > 0.f) ? 1.f : ((dotR < 0.f) ? -1.f : 0.f);
      float sgnG = (dotG > 0.f) ? 1.f : ((dotG < 0.f) ? -1.f : 0.f);
      float sR_ = sqrtf(d2R), sG_ = sqrtf(d2G);
      float o2h = sR_*sgnR, o2hg = sG_*sgnG;
      bool interior = dotR < 0.f;
      bool cmap = sG_ < 0.005f, rcmap = sR_ < 0.005f;
      penetr   += interior ? d2R : 0.f;
      nptsv    += cmap ? 1.f : 0.f;
      contactv += cmap ? d2P : 0.f;
      consistv += (cmap && rcmap) ? 1.f : 0.f;
      float w = (o2h < 0.f) ? 1.5f : (((o2hg < 0.01f) && (o2hg > -0.005f)) ? 1.f : 0.1f);
      lossov += fabsf(o2h - o2hg) * w;
    }
    float vals[5] = {penetr, nptsv, contactv, consistv, lossov};
    for (int q = 0; q < 5; ++q) {
      float s = wave_sum(vals[q]);
      if (lane == 0) red[wv][q] = s;
    }
    __syncthreads();
    if (tid < 5) {
      float s = red[0][tid] + red[1][tid] + red[2][tid] + red[3][tid];
      atomicAdd(&accs[tid], s);
    }
  } else {
    const int t = (bid - B_FIN_OBJ) * 256 + tid;
    float lossh = 0.f, rsum = 0.f, ksum = 0.f;
    if (t < NB * NH) {
      const float* rp = recon + (size_t)t * 3;
      const float* gp = gt + (size_t)t * 3;
      float d0 = rp[0]-gp[0], d1 = rp[1]-gp[1], d2 = rp[2]-gp[2];
      rsum = d0*d0 + d1*d1 + d2*d2;
      int j = t % NH;
      float h2o  = sqrtf(__uint_as_float(minHRb[t]));
      float h2og = sqrtf(__uint_as_float(minHGb[t]));
      lossh = fabsf(h2o - h2og) * powf(vw[j], 0.4f);
    }
    if (t < NB * NZ) {
      float m = mean[t], lv = logv[t];
      ksum = 1.f + lv - m*m - expf(lv);
    }
    float vals[3] = {lossh, rsum, ksum};
    for (int q = 0; q < 3; ++q) {
      float s = wave_sum(vals[q]);
      if (lane == 0) red[wv][q] = s;
    }
    __syncthreads();
    if (tid < 3) {
      float s = red[0][tid] + red[1][tid] + red[2][tid] + red[3][tid];
      atomicAdd(&accs[5 + tid], s);
    }
  }
  __syncthreads();
  if (tid == 0) {
    __threadfence();
    int* cnt = (int*)(accs + 8);
    int old = atomicAdd(cnt, 1);
    if (old == B_FIN - 1) {
      float a[8];
      for (int q = 0; q < 8; ++q) a[q] = atomicAdd(&accs[q], 0.0f);
      const float recon_loss = a[6] / (float)NB;
      const float kld = -0.5f * a[7] / (float)NB * 10.f;
      const float penetr = 100.f * a[0] / (float)NB;
      const float npts = a[1];
      const float contact = (npts > 0.f) ? (3000.f * a[2] / ((float)NB * npts)) : 0.f;
      const float consistency = -5.f * a[3] / (npts + 0.0001f);
      const float lossh = 35.f * (1.f - 0.005f) * (a[5] / (float)(NB * NH));
      const float losso = 30.f * (1.f - 0.005f) * (a[4] / (float)(NB * NO));
      out[0] = recon_loss + 0.1f*kld + 1000.f*penetr + 10.f*contact + 10.f*consistency + lossh + losso;
    }
  }
}

// =========================== PATH C (tiny ws) ===========================
__global__ __launch_bounds__(256) void obj_mono(
    const float* __restrict__ recon, const float* __restrict__ gt,
    const float* __restrict__ rnorm, const float* __restrict__ gnorm,
    const float* __restrict__ obj, float* __restrict__ accs)
{
  __shared__ float4 sR[NH];
  __shared__ float4 sG[NH];
  __shared__ float red[4][5];
  const int b = blockIdx.x / 12;
  const int tile = blockIdx.x % 12;
  const int tid = threadIdx.x;
  for (int i = tid; i < NH; i += 256) {
    const float* p = recon + ((size_t)b * NH + i) * 3;
    float x = p[0], y = p[1], z = p[2];
    sR[i] = make_float4(x, y, z, x*x + y*y + z*z);
    const float* q = gt + ((size_t)b * NH + i) * 3;
    float gx = q[0], gy = q[1], gz = q[2];
    sG[i] = make_float4(gx, gy, gz, gx*gx + gy*gy + gz*gz);
  }
  __syncthreads();
  const int o = tile * 256 + tid;
  float penetr = 0.f, nptsv = 0.f, contactv = 0.f, consistv = 0.f, lossov = 0.f;
  if (o < NO) {
    const float* op = obj + ((size_t)b * NO + o) * 3;
    const float ox = op[0], oy = op[1], oz = op[2];
    const float nx = -2.f*ox, ny = -2.f*oy, nz = -2.f*oz;
    const float o2 = ox*ox + oy*oy + oz*oz;
    float bR = 3.4e38f, bG = 3.4e38f; int iR = 0, iG = 0;
    for (int i = 0; i < NH; ++i) {
      float4 h = sR[i];
      float t = fmaf(nx, h.x, h.w); t = fmaf(ny, h.y, t); t = fmaf(nz, h.z, t);
      if (t < bR) { bR = t; iR = i; }
      float4 g = sG[i];
      float u = fmaf(nx, g.x, g.w); u = fmaf(ny, g.y, u); u = fmaf(nz, g.z, u);
      if (u < bG) { bG = u; iG = i; }
    }
    float bP = 3.4e38f;
    for (int k = 0; k < NP; ++k) {
      float4 h = sR[c_prior[k]];
      float t = fmaf(nx, h.x, h.w); t = fmaf(ny, h.y, t); t = fmaf(nz, h.z, t);
      bP = fminf(bP, t);
    }
    float d2R = fmaxf(bR + o2, 0.f);
    float d2G = fmaxf(bG + o2, 0.f);
    float d2P = fmaxf(bP + o2, 0.f);
    float4 hR = sR[iR];
    const float* nR = rnorm + ((size_t)b * NH + iR) * 3;
    float dotR = (ox-hR.x)*nR[0] + (oy-hR.y)*nR[1] + (oz-hR.z)*nR[2];
    float4 hG = sG[iG];
    const float* nG = gnorm + ((size_t)b * NH + iG) * 3;
    float dotG = (ox-hG.x)*nG[0] + (oy-hG.y)*nG[1] + (oz-hG.z)*nG[2];
    float sgnR = (dotR > 0.f) ? 1.f : ((dotR < 0.f) ? -1.f : 0.f);
    float sgnG = (dotG > 0.f) ? 1.f : ((dotG < 0.f) ? -1.f : 0.f);
    float sR_ = sqrtf(d2R), sG_ = sqrtf(d2G);
    float o2h = sR_*sgnR, o2hg = sG_*sgnG;
    bool interior = dotR < 0.f;
    bool cmap = sG_ < 0.005f, rcmap = sR_ < 0.005f;
    penetr = interior ? d2R : 0.f;
    nptsv = cmap ? 1.f : 0.f;
    contactv = cmap ? d2P : 0.f;
    consistv = (cmap && rcmap) ? 1.f : 0.f;
    float w = (o2h < 0.f) ? 1.5f : (((o2hg < 0.01f) && (o2hg > -0.005f)) ? 1.f : 0.1f);
    lossov = fabsf(o2h - o2hg) * w;
  }
  float vals[5] = {penetr, nptsv, contactv, consistv, lossov};
  const int lane = tid & 63, wv = tid >> 6;
  for (int q = 0; q < 5; ++q) {
    float s = wave_sum(vals[q]);
    if (lane == 0) red[wv][q] = s;
  }
  __syncthreads();
  if (tid < 5) {
    float s = red[0][tid] + red[1][tid] + red[2][tid] + red[3][tid];
    atomicAdd(&accs[tid], s);
  }
}

__global__ __launch_bounds__(256) void hand_full(
    const float* __restrict__ recon, const float* __restrict__ gt,
    const float* __restrict__ obj, const float* __restrict__ vw,
    float* __restrict__ accs)
{
  __shared__ float4 sO[500];
  __shared__ float red[4];
  const int b = blockIdx.x >> 2;
  const int j = ((blockIdx.x & 3) << 8) + threadIdx.x;
  const bool valid = j < NH;
  float rx=0,ry=0,rz=0,gx=0,gy=0,gz=0;
  if (valid) {
    const float* rp = recon + ((size_t)b * NH + j) * 3;
    const float* gp = gt + ((size_t)b * NH + j) * 3;
    rx=rp[0];ry=rp[1];rz=rp[2]; gx=gp[0];gy=gp[1];gz=gp[2];
  }
  const float nrx=-2.f*rx, nry=-2.f*ry, nrz=-2.f*rz;
  const float ngx=-2.f*gx, ngy=-2.f*gy, ngz=-2.f*gz;
  const float r2 = rx*rx+ry*ry+rz*rz, g2 = gx*gx+gy*gy+gz*gz;
  float mR = 3.4e38f, mG = 3.4e38f;
  for (int oc = 0; oc < 6; ++oc) {
    __syncthreads();
    const float* Ob = obj + ((size_t)b * NO + oc * 500) * 3;
    for (int i = threadIdx.x; i < 500; i += 256) {
      float x = Ob[3*i], y = Ob[3*i+1], z = Ob[3*i+2];
      sO[i] = make_float4(x, y, z, x*x + y*y + z*z);
    }
    __syncthreads();
    if (valid) {
      for (int k = 0; k < 500; ++k) {
        float4 o4 = sO[k];
        float t = fmaf(nrx,o4.x,o4.w); t = fmaf(nry,o4.y,t); t = fmaf(nrz,o4.z,t);
        mR = fminf(mR, t);
        float u = fmaf(ngx,o4.x,o4.w); u = fmaf(ngy,o4.y,u); u = fmaf(ngz,o4.z,u);
        mG = fminf(mG, u);
      }
    }
  }
  float lossh = valid ? fabsf(sqrtf(fmaxf(mR+r2,0.f)) - sqrtf(fmaxf(mG+g2,0.f))) * powf(vw[j], 0.4f) : 0.f;
  const int lane = threadIdx.x & 63, wv = threadIdx.x >> 6;
  float s = wave_sum(lossh);
  if (lane == 0) red[wv] = s;
  __syncthreads();
  if (threadIdx.x == 0) atomicAdd(&accs[5], red[0]+red[1]+red[2]+red[3]);
}

__global__ __launch_bounds__(256) void tail_nomins(
    const float* __restrict__ recon, const float* __restrict__ gt,
    const float* __restrict__ mean, const float* __restrict__ logv,
    float* __restrict__ accs)
{
  __shared__ float red[4][2];
  const int t = blockIdx.x * 256 + threadIdx.x;
  float rsum = 0.f, ksum = 0.f;
  if (t < NB * NH) {
    const float* rp = recon + (size_t)t * 3;
    const float* gp = gt + (size_t)t * 3;
    float d0 = rp[0]-gp[0], d1 = rp[1]-gp[1], d2 = rp[2]-gp[2];
    rsum = d0*d0 + d1*d1 + d2*d2;
  }
  if (t < NB * NZ) {
    float m = mean[t], lv = logv[t];
    ksum = 1.f + lv - m*m - expf(lv);
  }
  float vals[2] = {rsum, ksum};
  const int lane = threadIdx.x & 63, wv = threadIdx.x >> 6;
  for (int q = 0; q < 2; ++q) {
    float s = wave_sum(vals[q]);
    if (lane == 0) red[wv][q] = s;
  }
  __syncthreads();
  if (threadIdx.x < 2) {
    float s = red[0][threadIdx.x] + red[1][threadIdx.x] + red[2][threadIdx.x] + red[3][threadIdx.x];
    atomicAdd(&accs[6 + threadIdx.x], s);
  }
}

__global__ void init_small(float* accs) {
  int t = threadIdx.x;
  if (t < 8) accs[t] = 0.0f;
}

__global__ void final_fb(const float* __restrict__ a, float* __restrict__ out) {
  const float recon_loss = a[6] / (float)NB;
  const float kld = -0.5f * a[7] / (float)NB * 10.f;
  const float penetr = 100.f * a[0] / (float)NB;
  const float npts = a[1];
  const float contact = (npts > 0.f) ? (3000.f * a[2] / ((float)NB * npts)) : 0.f;
  const float consistency = -5.f * a[3] / (npts + 0.0001f);
  const float lossh = 35.f * (1.f - 0.005f) * (a[5] / (float)(NB * NH));
  const float losso = 30.f * (1.f - 0.005f) * (a[4] / (float)(NB * NO));
  out[0] = recon_loss + 0.1f*kld + 1000.f*penetr + 10.f*contact + 10.f*consistency + lossh + losso;
}

extern "C" void kernel_launch(void* const* d_in, const int* in_sizes, int n_in,
                              void* d_out, int out_size, void* d_ws, size_t ws_size,
                              hipStream_t stream) {
  const float* recon = (const float*)d_in[0];
  const float* gt    = (const float*)d_in[1];
  const float* rnorm = (const float*)d_in[2];
  const float* gnorm = (const float*)d_in[3];
  const float* obj   = (const float*)d_in[4];
  const float* mean  = (const float*)d_in[5];
  const float* logv  = (const float*)d_in[6];
  const float* vw    = (const float*)d_in[7];
  float* out = (float*)d_out;

  // PATH A layout
  float* accs = (float*)d_ws;
  float* keyR = accs + 16;                       // 4*96000
  float* keyG = keyR + (size_t)JSPLIT * NKEY;    // 4*96000
  float* minHR = keyG + (size_t)JSPLIT * NKEY;   // 12*24896
  float* minHG = minHR + (size_t)HC * NHT;       // 12*24896
  const size_t neededA = (16 + 2ull * JSPLIT * NKEY + 2ull * HC * NHT) * sizeof(float);

  // PATH B layout
  uint32* minHb = (uint32*)(accs + 16);
  ull* packO = (ull*)(minHb + N_MINH);
  const size_t neededB = 16 * sizeof(float) + (size_t)N_MINH * 4 + (size_t)N_PACK * 8;

  if (ws_size >= neededA) {
    mega1a<<<OBJ_BLKS + HAND_BLKS, 256, 0, stream>>>(
        recon, gt, obj, keyR, keyG, minHR, minHG, accs);
    mega2a<<<FIN_BLKS, 256, 0, stream>>>(
        recon, gt, rnorm, gnorm, obj, mean, logv, vw,
        keyR, keyG, minHR, minHG, accs, out);
  } else if (ws_size >= neededB) {
    init_b<<<(N_PACK + 255) / 256, 256, 0, stream>>>(accs, minHb, packO);
    mega1b<<<B_OBJ_BLKS + B_HAND_BLKS, 256, 0, stream>>>(
        recon, gt, obj, minHb, minHb + NB * NH, packO, packO + NB * NO);
    mega2b<<<B_FIN, 256, 0, stream>>>(
        recon, gt, rnorm, gnorm, obj, mean, logv, vw,
        minHb, minHb + NB * NH, packO, packO + NB * NO, accs, out);
  } else {
    init_small<<<1, 64, 0, stream>>>(accs);
    obj_mono<<<NB * 12, 256, 0, stream>>>(recon, gt, rnorm, gnorm, obj, accs);
    hand_full<<<NB * 4, 256, 0, stream>>>(recon, gt, obj, vw, accs);
    tail_nomins<<<(NB * NH + 255) / 256, 256, 0, stream>>>(recon, gt, mean, logv, accs);
    final_fb<<<1, 1, 0, stream>>>(accs, out);
  }
}